// Round 8
// baseline (724.847 us; speedup 1.0000x reference)
//
#include <hip/hip_runtime.h>
#include <math.h>

#define H 256
#define L 32
#define HEADS 4
#define FEAT 7
#define LN_EPS 1e-5f

typedef __attribute__((ext_vector_type(8))) short bf16x8;
typedef __attribute__((ext_vector_type(4))) float f32x4;

__device__ __forceinline__ float wave_reduce_sum64(float v) {
#pragma unroll
  for (int m = 32; m >= 1; m >>= 1) v += __shfl_xor(v, m, 64);
  return v;
}

__device__ __forceinline__ short bf16rne(float f) {
  unsigned u = __float_as_uint(f);
  unsigned r = (u + 0x7FFFu + ((u >> 16) & 1u)) >> 16;
  return (short)r;
}

__device__ __forceinline__ float bf2f(short s) {
  return __uint_as_float(((unsigned)(unsigned short)s) << 16);
}

// ---------------- ONE prep kernel: all weight packing + folded mats + biases
// grid ranges: [0,32) w2P | [32,160) wqp | [160,288) wbig | [288,544) 4x pack512 | [544,548) bias_p | 548 bias_out
__global__ __launch_bounds__(256) void k_prep(
    const float* __restrict__ pe_w2, const float* __restrict__ aiw, const float* __restrict__ aow,
    const float* __restrict__ aib, const float* __restrict__ aob,
    const float* __restrict__ gate_w, const float* __restrict__ trans_w, const float* __restrict__ mp_w,
    short* __restrict__ w2P, short* __restrict__ wqpP, short* __restrict__ wbigP,
    short* __restrict__ gwP, short* __restrict__ twP, short* __restrict__ mp0P, short* __restrict__ mp1P,
    float* __restrict__ bias_p, float* __restrict__ bias_out) {
  const int bb = blockIdx.x;
  const int tid = threadIdx.x;
  if (bb < 32) {
    // pack pe_w2 (K=256, N=256): frag order
    const int t = bb * 256 + tid;
    const int lane = t & 63;
    const int ks = (t >> 6) & 7;
    const int tcol = (t >> 6) >> 3;
    const int j = tcol * 16 + (lane & 15);
    const int k0 = ks * 32 + (lane >> 4) * 8;
    short v[8];
#pragma unroll
    for (int i = 0; i < 8; ++i) v[i] = bf16rne(pe_w2[(size_t)(k0 + i) * 256 + j]);
    *(int4*)&w2P[(size_t)t * 8] = *(int4*)v;
  } else if (bb < 160) {
    // Wqp[k, hc] = 0.125 * sum_d wq[k,h*64+d]*wk[c,h*64+d]  (N=1024, K=256)
    const int t = (bb - 32) * 256 + tid;
    const int lane = t & 63;
    const int ks = (t >> 6) & 7;
    const int tcol = t >> 9;
    const int col = tcol * 16 + (lane & 15);
    const int h = col >> 8, c = col & 255;
    const int k0 = ks * 32 + (lane >> 4) * 8;
    short v[8];
#pragma unroll
    for (int i = 0; i < 8; ++i) {
      const int k = k0 + i;
      float s = 0.f;
      for (int d = 0; d < 64; d += 4) {
        const float4 qa = *(const float4*)&aiw[(size_t)k * 768 + h * 64 + d];
        const float4 ka = *(const float4*)&aiw[(size_t)c * 768 + 256 + h * 64 + d];
        s = fmaf(qa.x, ka.x, fmaf(qa.y, ka.y, fmaf(qa.z, ka.z, fmaf(qa.w, ka.w, s))));
      }
      v[i] = bf16rne(0.125f * s);
    }
    *(int4*)&wqpP[(size_t)t * 8] = *(int4*)v;
  } else if (bb < 288) {
    // Wbig with K-reorder k' = c*4 + h: Wbig[k'][j] = sum_d wv[c,h*64+d]*aow[h*64+d][j]  (N=256, K=1024)
    const int t = (bb - 160) * 256 + tid;
    const int lane = t & 63;
    const int ks = (t >> 6) & 31;
    const int tcol = t >> 11;
    const int j = tcol * 16 + (lane & 15);
    const int k0 = ks * 32 + (lane >> 4) * 8;
    short v[8];
#pragma unroll
    for (int i = 0; i < 8; ++i) {
      const int k = k0 + i;
      const int c = k >> 2, h = k & 3;
      float s = 0.f;
      for (int d = 0; d < 64; ++d)
        s = fmaf(aiw[(size_t)c * 768 + 512 + h * 64 + d], aow[(size_t)(h * 64 + d) * 256 + j], s);
      v[i] = bf16rne(s);
    }
    *(int4*)&wbigP[(size_t)t * 8] = *(int4*)v;
  } else if (bb < 544) {
    // pack 4 mats of K=512,N=256
    const int sub = bb - 288;
    const int mi = sub >> 6;
    const float* W = (mi == 0) ? gate_w : (mi == 1) ? trans_w : (mi == 2) ? mp_w : (mp_w + 512 * 256);
    short* P = (mi == 0) ? gwP : (mi == 1) ? twP : (mi == 2) ? mp0P : mp1P;
    const int t = (sub & 63) * 256 + tid;
    const int lane = t & 63;
    const int ks = (t >> 6) & 15;
    const int tcol = (t >> 6) >> 4;
    const int j = tcol * 16 + (lane & 15);
    const int k0 = ks * 32 + (lane >> 4) * 8;
    short v[8];
#pragma unroll
    for (int i = 0; i < 8; ++i) v[i] = bf16rne(W[(size_t)(k0 + i) * 256 + j]);
    *(int4*)&P[(size_t)t * 8] = *(int4*)v;
  } else if (bb < 548) {
    const int col = (bb - 544) * 256 + tid;  // 1024
    const int h = col >> 8, c = col & 255;
    float s = 0.f;
    for (int d = 0; d < 64; ++d)
      s = fmaf(aib[h * 64 + d], aiw[(size_t)c * 768 + 256 + h * 64 + d], s);
    bias_p[col] = 0.125f * s;
  } else {
    const int j = tid;  // 256
    float s = aob[j];
    for (int e2 = 0; e2 < 256; ++e2) s = fmaf(aib[512 + e2], aow[(size_t)e2 * 256 + j], s);
    bias_out[j] = s;
  }
}

// ---------------- encoder (MFMA): h1 = relu(cf@w1+b1); enc = h1@w2+b2 (bf16); p = enc@Wqp + bias_p
__global__ __launch_bounds__(256) void k_enc_mfma(
    const float* __restrict__ cf, const float* __restrict__ pe_w1, const float* __restrict__ pe_b1,
    const short* __restrict__ w2P, const float* __restrict__ pe_b2,
    const short* __restrict__ wqpP, const float* __restrict__ bias_p,
    short* __restrict__ enc_bf16, short* __restrict__ p_bf16, int n) {
  __shared__ float cfs[32][FEAT];
  __shared__ short h1[32][264];
  __shared__ short encS[32][264];
  const int tid = threadIdx.x;
  const int lane = tid & 63, w = tid >> 6;
  const int n0 = blockIdx.x * 32;
  for (int idx = tid; idx < 32 * FEAT; idx += 256) cfs[idx / FEAT][idx % FEAT] = cf[(size_t)n0 * FEAT + idx];
  __syncthreads();
  {
    const int j = tid;
    float wv[FEAT];
#pragma unroll
    for (int f = 0; f < FEAT; ++f) wv[f] = pe_w1[f * H + j];
    const float b1v = pe_b1[j];
    for (int r = 0; r < 32; ++r) {
      float s = b1v;
#pragma unroll
      for (int f = 0; f < FEAT; ++f) s = fmaf(cfs[r][f], wv[f], s);
      h1[r][j] = bf16rne(fmaxf(s, 0.f));
    }
  }
  __syncthreads();
  const int arow = lane & 15;
  const int koff = (lane >> 4) * 8;
  {
    f32x4 acc[2][4];
#pragma unroll
    for (int rt = 0; rt < 2; ++rt)
#pragma unroll
      for (int ct = 0; ct < 4; ++ct) acc[rt][ct] = (f32x4)0.f;
#pragma unroll
    for (int ks = 0; ks < 8; ++ks) {
      const int k0 = ks * 32 + koff;
      const bf16x8 a0 = *(const bf16x8*)&h1[arow][k0];
      const bf16x8 a1 = *(const bf16x8*)&h1[16 + arow][k0];
#pragma unroll
      for (int ct = 0; ct < 4; ++ct) {
        const size_t fo = (((size_t)(w * 4 + ct) * 8 + ks) * 64 + lane) * 8;
        const bf16x8 b = *(const bf16x8*)&w2P[fo];
        acc[0][ct] = __builtin_amdgcn_mfma_f32_16x16x32_bf16(a0, b, acc[0][ct], 0, 0, 0);
        acc[1][ct] = __builtin_amdgcn_mfma_f32_16x16x32_bf16(a1, b, acc[1][ct], 0, 0, 0);
      }
    }
#pragma unroll
    for (int rt = 0; rt < 2; ++rt)
#pragma unroll
      for (int ct = 0; ct < 4; ++ct) {
        const int col = w * 64 + ct * 16 + (lane & 15);
        const float b2v = pe_b2[col];
#pragma unroll
        for (int i = 0; i < 4; ++i) {
          const int row = rt * 16 + (lane >> 4) * 4 + i;
          const short bv = bf16rne(acc[rt][ct][i] + b2v);
          encS[row][col] = bv;
          enc_bf16[(size_t)(n0 + row) * H + col] = bv;
        }
      }
  }
  __syncthreads();
#pragma unroll
  for (int chunk = 0; chunk < 2; ++chunk) {
    f32x4 acc[2][8];
#pragma unroll
    for (int rt = 0; rt < 2; ++rt)
#pragma unroll
      for (int c8 = 0; c8 < 8; ++c8) acc[rt][c8] = (f32x4)0.f;
#pragma unroll
    for (int ks = 0; ks < 8; ++ks) {
      const int k0 = ks * 32 + koff;
      const bf16x8 a0 = *(const bf16x8*)&encS[arow][k0];
      const bf16x8 a1 = *(const bf16x8*)&encS[16 + arow][k0];
#pragma unroll
      for (int c8 = 0; c8 < 8; ++c8) {
        const int tcol = w * 16 + chunk * 8 + c8;
        const size_t fo = (((size_t)tcol * 8 + ks) * 64 + lane) * 8;
        const bf16x8 b = *(const bf16x8*)&wqpP[fo];
        acc[0][c8] = __builtin_amdgcn_mfma_f32_16x16x32_bf16(a0, b, acc[0][c8], 0, 0, 0);
        acc[1][c8] = __builtin_amdgcn_mfma_f32_16x16x32_bf16(a1, b, acc[1][c8], 0, 0, 0);
      }
    }
#pragma unroll
    for (int rt = 0; rt < 2; ++rt)
#pragma unroll
      for (int c8 = 0; c8 < 8; ++c8) {
        const int col = w * 256 + (chunk * 8 + c8) * 16 + (lane & 15);
        const float bp = bias_p[col];
#pragma unroll
        for (int i = 0; i < 4; ++i) {
          const int row = rt * 16 + (lane >> 4) * 4 + i;
          p_bf16[(size_t)(n0 + row) * 1024 + col] = bf16rne(acc[rt][c8][i] + bp);
        }
      }
  }
}

// ---------------- per-clause attention: float4-staged bf16 lit, MFMA scores, coalesced m-store
// m layout: k' = c*4 + h  (matches Wbig packing)
__global__ __launch_bounds__(256) void k_attn(
    const float* __restrict__ lit, const int* __restrict__ mask,
    const short* __restrict__ p_in, short* __restrict__ m_out,
    short* __restrict__ litmean_bf, int* __restrict__ flags, int n) {
  __shared__ short lit_bs[32][264];
  __shared__ float attn_s[32][4];
  __shared__ int validS[32];
  __shared__ int nvalidS;
  const int j = threadIdx.x;
  const int nn = blockIdx.x;
  const float* litrow = lit + (size_t)nn * (L * H);
#pragma unroll
  for (int t = 0; t < 8; ++t) {
    const int idx = (t * 256 + j) << 2;
    const int r = idx >> 8, c = idx & 255;
    const float4 f = *(const float4*)&litrow[idx];
    short4 hv;
    hv.x = bf16rne(f.x); hv.y = bf16rne(f.y); hv.z = bf16rne(f.z); hv.w = bf16rne(f.w);
    *(short4*)&lit_bs[r][c] = hv;
  }
  if (j < 32) validS[j] = (mask[(size_t)nn * L + j] != 0) ? 1 : 0;
  __syncthreads();
  if (j == 0) {
    int c = 0;
#pragma unroll
    for (int l = 0; l < 32; ++l) c += validS[l];
    nvalidS = c;
  }
  __syncthreads();
  const int nvalid = nvalidS;
  const bool allm = (nvalid == 0);
  if (j < 64) {
    const int lane = j;
    f32x4 sc0 = (f32x4)0.f, sc1 = (f32x4)0.f;
    const int hh = lane & 3;
    const int krow = (lane >> 4) * 8;
    const short* prow = p_in + (size_t)nn * 1024 + hh * 256;
#pragma unroll
    for (int ks = 0; ks < 8; ++ks) {
      const bf16x8 a = *(const bf16x8*)&prow[ks * 32 + krow];
      const bf16x8 b0 = *(const bf16x8*)&lit_bs[lane & 15][ks * 32 + krow];
      const bf16x8 b1 = *(const bf16x8*)&lit_bs[16 + (lane & 15)][ks * 32 + krow];
      sc0 = __builtin_amdgcn_mfma_f32_16x16x32_bf16(a, b0, sc0, 0, 0, 0);
      sc1 = __builtin_amdgcn_mfma_f32_16x16x32_bf16(a, b1, sc1, 0, 0, 0);
    }
    if (lane < 16) {
      const int l0 = lane, l1 = 16 + lane;
      const bool ok0 = validS[l0] || (allm && l0 == 0);
      const bool ok1 = validS[l1] != 0;
#pragma unroll
      for (int i = 0; i < 4; ++i) {
        float s0 = ok0 ? sc0[i] : -INFINITY;
        float s1 = ok1 ? sc1[i] : -INFINITY;
        float mx = fmaxf(s0, s1);
#pragma unroll
        for (int m = 8; m >= 1; m >>= 1) mx = fmaxf(mx, __shfl_xor(mx, m, 16));
        float e0 = ok0 ? __expf(s0 - mx) : 0.f;
        float e1 = ok1 ? __expf(s1 - mx) : 0.f;
        float sm = e0 + e1;
#pragma unroll
        for (int m = 8; m >= 1; m >>= 1) sm += __shfl_xor(sm, m, 16);
        const float inv = 1.f / sm;
        attn_s[l0][i] = e0 * inv;
        attn_s[l1][i] = e1 * inv;
      }
    }
  }
  __syncthreads();
  {
    const float inv = 1.f / fmaxf((float)nvalid, 1.f);
    float lm = 0.f;
    float mm0 = 0.f, mm1 = 0.f, mm2 = 0.f, mm3 = 0.f;
#pragma unroll
    for (int l = 0; l < 32; ++l) {
      const float lv = bf2f(lit_bs[l][j]);
      if (validS[l]) lm += lv;
      const float4 av = *(const float4*)&attn_s[l][0];
      mm0 = fmaf(av.x, lv, mm0);
      mm1 = fmaf(av.y, lv, mm1);
      mm2 = fmaf(av.z, lv, mm2);
      mm3 = fmaf(av.w, lv, mm3);
    }
    litmean_bf[(size_t)nn * H + j] = bf16rne(lm * inv);
    short4 mv;
    mv.x = bf16rne(mm0); mv.y = bf16rne(mm1); mv.z = bf16rne(mm2); mv.w = bf16rne(mm3);
    *(short4*)&m_out[(size_t)nn * 1024 + j * 4] = mv;  // k' = j*4 + h
  }
  if (j == 0) flags[nn] = allm ? 1 : 0;
}

// ---------------- fused: ctx/out-proj GEMM (K'=1024) + LN1 + gate/trans GEMMs + fusion LN -> x0 bf16
__global__ __launch_bounds__(256) void k_fused(
    const short* __restrict__ m_bf16, const short* __restrict__ wbigP, const float* __restrict__ bias_out,
    const short* __restrict__ enc_bf16, const short* __restrict__ litmean_bf, const int* __restrict__ flags,
    const float* __restrict__ ag, const float* __restrict__ ab,
    const short* __restrict__ gwP, const short* __restrict__ twP,
    const float* __restrict__ gb, const float* __restrict__ tb,
    const float* __restrict__ fg, const float* __restrict__ fb,
    short* __restrict__ xout_bf, int n) {
  __shared__ short As[32][520];
  __shared__ float v_s[32][260];
  __shared__ float mu_s[32], sg_s[32];
  __shared__ int flagS[32];
  const int tid = threadIdx.x;
  const int lane = tid & 63, w = tid >> 6;
  const int n0 = blockIdx.x * 32;
  for (int q8 = tid; q8 < 32 * 32; q8 += 256) {
    const int idx = q8 << 3;
    const int r = idx >> 8, c = idx & 255;
    *(int4*)&As[r][256 + c] = *(const int4*)&enc_bf16[(size_t)(n0 + r) * H + c];
  }
  if (tid < 32) flagS[tid] = flags[n0 + tid];
  const int arow = lane & 15;
  const int koff = (lane >> 4) * 8;
  f32x4 acc[2][4];
#pragma unroll
  for (int rt = 0; rt < 2; ++rt)
#pragma unroll
    for (int ct = 0; ct < 4; ++ct) acc[rt][ct] = (f32x4)0.f;
#pragma unroll 8
  for (int ks = 0; ks < 32; ++ks) {
    const size_t abase = (size_t)(n0 + arow) * 1024 + ks * 32 + koff;
    const bf16x8 a0 = *(const bf16x8*)&m_bf16[abase];
    const bf16x8 a1 = *(const bf16x8*)&m_bf16[abase + 16 * 1024];
#pragma unroll
    for (int ct = 0; ct < 4; ++ct) {
      const size_t fo = (((size_t)(w * 4 + ct) * 32 + ks) * 64 + lane) * 8;
      const bf16x8 bw = *(const bf16x8*)&wbigP[fo];
      acc[0][ct] = __builtin_amdgcn_mfma_f32_16x16x32_bf16(a0, bw, acc[0][ct], 0, 0, 0);
      acc[1][ct] = __builtin_amdgcn_mfma_f32_16x16x32_bf16(a1, bw, acc[1][ct], 0, 0, 0);
    }
  }
  __syncthreads();
#pragma unroll
  for (int rt = 0; rt < 2; ++rt)
#pragma unroll
    for (int ct = 0; ct < 4; ++ct) {
      const int col = w * 64 + ct * 16 + (lane & 15);
      const float bo = bias_out[col];
#pragma unroll
      for (int i = 0; i < 4; ++i) {
        const int row = rt * 16 + (lane >> 4) * 4 + i;
        const float o = flagS[row] ? 0.f : (acc[rt][ct][i] + bo);
        v_s[row][col] = o + bf2f(As[row][256 + col]);
      }
    }
  __syncthreads();
  for (int r = w; r < 32; r += 4) {
    float ps = 0.f, pq = 0.f;
#pragma unroll
    for (int t = 0; t < 4; ++t) {
      float v = v_s[r][lane + 64 * t];
      ps += v;
      pq = fmaf(v, v, pq);
    }
    ps = wave_reduce_sum64(ps);
    pq = wave_reduce_sum64(pq);
    if (lane == 0) {
      float mu = ps * (1.f / H);
      mu_s[r] = mu;
      sg_s[r] = rsqrtf(pq * (1.f / H) - mu * mu + LN_EPS);
    }
  }
  __syncthreads();
  {
    const float agv = ag[tid], abv = ab[tid];
    for (int r = 0; r < 32; ++r) {
      const float val = (v_s[r][tid] - mu_s[r]) * sg_s[r] * agv + abv +
                        bf2f(litmean_bf[(size_t)(n0 + r) * H + tid]);
      As[r][tid] = bf16rne(val);
    }
  }
  __syncthreads();
  f32x4 accg[2][4], acct[2][4];
#pragma unroll
  for (int rt = 0; rt < 2; ++rt)
#pragma unroll
    for (int ct = 0; ct < 4; ++ct) { accg[rt][ct] = (f32x4)0.f; acct[rt][ct] = (f32x4)0.f; }
#pragma unroll 4
  for (int ks = 0; ks < 16; ++ks) {
    const int k0 = ks * 32 + koff;
    const bf16x8 a0 = *(const bf16x8*)&As[arow][k0];
    const bf16x8 a1 = *(const bf16x8*)&As[16 + arow][k0];
#pragma unroll
    for (int ct = 0; ct < 4; ++ct) {
      const size_t fo = (((size_t)(w * 4 + ct) * 16 + ks) * 64 + lane) * 8;
      const bf16x8 bg = *(const bf16x8*)&gwP[fo];
      const bf16x8 bt = *(const bf16x8*)&twP[fo];
      accg[0][ct] = __builtin_amdgcn_mfma_f32_16x16x32_bf16(a0, bg, accg[0][ct], 0, 0, 0);
      accg[1][ct] = __builtin_amdgcn_mfma_f32_16x16x32_bf16(a1, bg, accg[1][ct], 0, 0, 0);
      acct[0][ct] = __builtin_amdgcn_mfma_f32_16x16x32_bf16(a0, bt, acct[0][ct], 0, 0, 0);
      acct[1][ct] = __builtin_amdgcn_mfma_f32_16x16x32_bf16(a1, bt, acct[1][ct], 0, 0, 0);
    }
  }
#pragma unroll
  for (int rt = 0; rt < 2; ++rt)
#pragma unroll
    for (int ct = 0; ct < 4; ++ct) {
      const int col = w * 64 + ct * 16 + (lane & 15);
      const float gbv = gb[col], tbv = tb[col];
#pragma unroll
      for (int i = 0; i < 4; ++i) {
        const int rl = rt * 16 + (lane >> 4) * 4 + i;
        const float gate = 1.f / (1.f + __expf(-(accg[rt][ct][i] + gbv)));
        const float tr = acct[rt][ct][i] + tbv;
        const float a = bf2f(As[rl][col]);
        v_s[rl][col] = fmaf(gate, a - tr, tr);
      }
    }
  __syncthreads();
  for (int r = w; r < 32; r += 4) {
    float ps = 0.f, pq = 0.f;
#pragma unroll
    for (int t = 0; t < 4; ++t) {
      float v = v_s[r][lane + 64 * t];
      ps += v;
      pq = fmaf(v, v, pq);
    }
    ps = wave_reduce_sum64(ps);
    pq = wave_reduce_sum64(pq);
    if (lane == 0) {
      float mu = ps * (1.f / H);
      mu_s[r] = mu;
      sg_s[r] = rsqrtf(pq * (1.f / H) - mu * mu + LN_EPS);
    }
  }
  __syncthreads();
  {
    const float fgv = fg[tid], fbv = fb[tid];
    for (int r = 0; r < 32; ++r)
      xout_bf[(size_t)(n0 + r) * H + tid] = bf16rne((v_s[r][tid] - mu_s[r]) * sg_s[r] * fgv + fbv);
  }
}

// ---------------- mp layer with FUSED gather: agg gathered into LDS, then GEMM + LN
__global__ __launch_bounds__(256) void k_mp_mfma(
    const short* __restrict__ xin_bf, const int* __restrict__ edge_src, const int* __restrict__ row_ptr,
    const short* __restrict__ wP, const float* __restrict__ bias,
    const float* __restrict__ g, const float* __restrict__ b,
    float* __restrict__ xout_f32, short* __restrict__ xout_bf, int n) {
  __shared__ short As[32][520];
  __shared__ float v_s[32][260];
  __shared__ float mu_s[32], sg_s[32];
  const int tid = threadIdx.x;
  const int lane = tid & 63, w = tid >> 6;
  const int n0 = blockIdx.x * 32;
  // stage x rows (cols 0-255)
  for (int q8 = tid; q8 < 32 * 32; q8 += 256) {
    const int idx = q8 << 3;
    const int r = idx >> 8, c = idx & 255;
    *(int4*)&As[r][c] = *(const int4*)&xin_bf[(size_t)(n0 + r) * H + c];
  }
  // gather: wave w handles rows w, w+4, ... (cols 256-511)
  for (int rr = w; rr < 32; rr += 4) {
    const int d = n0 + rr;
    const int beg = row_ptr[d], end = row_ptr[d + 1];
    float4 acc = {0.f, 0.f, 0.f, 0.f};
    int i = beg;
    for (; i + 4 <= end; i += 4) {
      const int s0 = edge_src[i], s1 = edge_src[i + 1], s2 = edge_src[i + 2], s3 = edge_src[i + 3];
      const short4 v0 = *(const short4*)(xin_bf + (size_t)s0 * H + lane * 4);
      const short4 v1 = *(const short4*)(xin_bf + (size_t)s1 * H + lane * 4);
      const short4 v2 = *(const short4*)(xin_bf + (size_t)s2 * H + lane * 4);
      const short4 v3 = *(const short4*)(xin_bf + (size_t)s3 * H + lane * 4);
      acc.x += bf2f(v0.x) + bf2f(v1.x) + bf2f(v2.x) + bf2f(v3.x);
      acc.y += bf2f(v0.y) + bf2f(v1.y) + bf2f(v2.y) + bf2f(v3.y);
      acc.z += bf2f(v0.z) + bf2f(v1.z) + bf2f(v2.z) + bf2f(v3.z);
      acc.w += bf2f(v0.w) + bf2f(v1.w) + bf2f(v2.w) + bf2f(v3.w);
    }
    for (; i < end; ++i) {
      const int s = edge_src[i];
      const short4 v = *(const short4*)(xin_bf + (size_t)s * H + lane * 4);
      acc.x += bf2f(v.x); acc.y += bf2f(v.y); acc.z += bf2f(v.z); acc.w += bf2f(v.w);
    }
    const float inv = 1.f / fmaxf((float)(end - beg), 1.f);
    short4 o;
    o.x = bf16rne(acc.x * inv); o.y = bf16rne(acc.y * inv);
    o.z = bf16rne(acc.z * inv); o.w = bf16rne(acc.w * inv);
    *(short4*)&As[rr][256 + lane * 4] = o;
  }
  __syncthreads();
  f32x4 acc[2][4];
#pragma unroll
  for (int rt = 0; rt < 2; ++rt)
#pragma unroll
    for (int ct = 0; ct < 4; ++ct) acc[rt][ct] = (f32x4)0.f;
  const int arow = lane & 15;
  const int koff = (lane >> 4) * 8;
#pragma unroll 4
  for (int ks = 0; ks < 16; ++ks) {
    const int k0 = ks * 32 + koff;
    const bf16x8 a0 = *(const bf16x8*)&As[arow][k0];
    const bf16x8 a1 = *(const bf16x8*)&As[16 + arow][k0];
#pragma unroll
    for (int ct = 0; ct < 4; ++ct) {
      const size_t fo = (((size_t)(w * 4 + ct) * 16 + ks) * 64 + lane) * 8;
      const bf16x8 bw = *(const bf16x8*)&wP[fo];
      acc[0][ct] = __builtin_amdgcn_mfma_f32_16x16x32_bf16(a0, bw, acc[0][ct], 0, 0, 0);
      acc[1][ct] = __builtin_amdgcn_mfma_f32_16x16x32_bf16(a1, bw, acc[1][ct], 0, 0, 0);
    }
  }
#pragma unroll
  for (int rt = 0; rt < 2; ++rt)
#pragma unroll
    for (int ct = 0; ct < 4; ++ct) {
      const int col = w * 64 + ct * 16 + (lane & 15);
      const float bsv = bias[col];
#pragma unroll
      for (int i = 0; i < 4; ++i) {
        const int rl = rt * 16 + (lane >> 4) * 4 + i;
        const float u = fmaxf(acc[rt][ct][i] + bsv, 0.f);
        v_s[rl][col] = bf2f(As[rl][col]) + u;
      }
    }
  __syncthreads();
  for (int r = w; r < 32; r += 4) {
    float ps = 0.f, pq = 0.f;
#pragma unroll
    for (int t = 0; t < 4; ++t) {
      float v = v_s[r][lane + 64 * t];
      ps += v;
      pq = fmaf(v, v, pq);
    }
    ps = wave_reduce_sum64(ps);
    pq = wave_reduce_sum64(pq);
    if (lane == 0) {
      float mu = ps * (1.f / H);
      mu_s[r] = mu;
      sg_s[r] = rsqrtf(pq * (1.f / H) - mu * mu + LN_EPS);
    }
  }
  __syncthreads();
  const float gv = g[tid], bv = b[tid];
  for (int r = 0; r < 32; ++r) {
    const float val = (v_s[r][tid] - mu_s[r]) * sg_s[r] * gv + bv;
    if (xout_f32) xout_f32[(size_t)(n0 + r) * H + tid] = val;
    if (xout_bf) xout_bf[(size_t)(n0 + r) * H + tid] = bf16rne(val);
  }
}

// ---------------- CSR build
__global__ void k_zero_int(int* __restrict__ p, int count) {
  int i = blockIdx.x * blockDim.x + threadIdx.x;
  if (i < count) p[i] = 0;
}

__global__ void k_hist(const int* __restrict__ dst, int* __restrict__ hist, int e) {
  int i = blockIdx.x * blockDim.x + threadIdx.x;
  if (i < e) atomicAdd(&hist[dst[i]], 1);
}

__global__ __launch_bounds__(1024) void k_scan(
    const int* __restrict__ hist, int* __restrict__ row_ptr, int* __restrict__ cursor, int n, int e) {
  __shared__ int part[1024];
  const int t = threadIdx.x;
  const int chunk = (n + 1023) / 1024;
  const int lo = t * chunk;
  const int hi = min(lo + chunk, n);
  int s = 0;
  for (int i = lo; i < hi; ++i) s += hist[i];
  part[t] = s;
  __syncthreads();
  for (int d = 1; d < 1024; d <<= 1) {
    int v = (t >= d) ? part[t - d] : 0;
    __syncthreads();
    part[t] += v;
    __syncthreads();
  }
  int run = (t > 0) ? part[t - 1] : 0;
  for (int i = lo; i < hi; ++i) {
    row_ptr[i] = run;
    cursor[i] = run;
    run += hist[i];
  }
  if (t == 1023) row_ptr[n] = e;
}

__global__ void k_fill(const int* __restrict__ adj, int* __restrict__ cursor,
                       int* __restrict__ edge_src, int e) {
  int i = blockIdx.x * blockDim.x + threadIdx.x;
  if (i < e) {
    int s = adj[i], d = adj[e + i];
    int pos = atomicAdd(&cursor[d], 1);
    edge_src[pos] = s;
  }
}

extern "C" void kernel_launch(void* const* d_in, const int* in_sizes, int n_in,
                              void* d_out, int out_size, void* d_ws, size_t ws_size,
                              hipStream_t stream) {
  const float* lit = (const float*)d_in[0];
  const float* cf = (const float*)d_in[1];
  const int* mask = (const int*)d_in[2];
  const int* adj = (const int*)d_in[3];
  const float* pe_w1 = (const float*)d_in[4];
  const float* pe_b1 = (const float*)d_in[5];
  const float* pe_w2 = (const float*)d_in[6];
  const float* pe_b2 = (const float*)d_in[7];
  const float* aiw = (const float*)d_in[8];
  const float* aib = (const float*)d_in[9];
  const float* aow = (const float*)d_in[10];
  const float* aob = (const float*)d_in[11];
  const float* attn_ln_g = (const float*)d_in[12];
  const float* attn_ln_b = (const float*)d_in[13];
  const float* gate_w = (const float*)d_in[14];
  const float* gate_b = (const float*)d_in[15];
  const float* trans_w = (const float*)d_in[16];
  const float* trans_b = (const float*)d_in[17];
  const float* fus_ln_g = (const float*)d_in[18];
  const float* fus_ln_b = (const float*)d_in[19];
  const float* mp_w = (const float*)d_in[20];
  const float* mp_b = (const float*)d_in[21];
  const float* mp_ln_g = (const float*)d_in[22];
  const float* mp_ln_b = (const float*)d_in[23];

  const int n = in_sizes[1] / FEAT;   // 20000
  const int e = in_sizes[3] / 2;      // 640000

  float* ws = (float*)d_ws;
  size_t off = 0;
  short* enc_bf16 = (short*)(ws + off); off += (size_t)n * 128;
  short* pm_bf16 = (short*)(ws + off); off += (size_t)n * 512;   // p then m (in-place)
  short* litmean_bf = (short*)(ws + off); off += (size_t)n * 128;
  short* x0_bf = (short*)(ws + off); off += (size_t)n * 128;
  short* x1_bf = (short*)(ws + off); off += (size_t)n * 128;
  int* flags = (int*)(ws + off); off += n;
  int* hist = (int*)(ws + off); off += n;
  int* row_ptr = (int*)(ws + off); off += n + 2;
  int* cursor = (int*)(ws + off); off += n;
  int* edge_src = (int*)(ws + off); off += e;
  short* w2P = (short*)(ws + off); off += 256 * 256 / 2;
  short* wqpP = (short*)(ws + off); off += 256 * 1024 / 2;
  short* wbigP = (short*)(ws + off); off += 1024 * 256 / 2;
  short* gwP = (short*)(ws + off); off += 512 * 256 / 2;
  short* twP = (short*)(ws + off); off += 512 * 256 / 2;
  short* mp0P = (short*)(ws + off); off += 512 * 256 / 2;
  short* mp1P = (short*)(ws + off); off += 512 * 256 / 2;
  float* bias_p = ws + off; off += 1024;
  float* bias_out = ws + off; off += 256;

  dim3 blk(256);
  k_prep<<<549, blk, 0, stream>>>(pe_w2, aiw, aow, aib, aob, gate_w, trans_w, mp_w,
                                  w2P, wqpP, wbigP, gwP, twP, mp0P, mp1P, bias_p, bias_out);

  k_enc_mfma<<<n / 32, blk, 0, stream>>>(cf, pe_w1, pe_b1, w2P, pe_b2, wqpP, bias_p, enc_bf16, pm_bf16, n);
  k_attn<<<n, blk, 0, stream>>>(lit, mask, pm_bf16, pm_bf16, litmean_bf, flags, n);

  // CSR build
  k_zero_int<<<(n + 255) / 256, blk, 0, stream>>>(hist, n);
  k_hist<<<(e + 255) / 256, blk, 0, stream>>>(adj + e, hist, e);
  k_scan<<<1, 1024, 0, stream>>>(hist, row_ptr, cursor, n, e);
  k_fill<<<(e + 255) / 256, blk, 0, stream>>>(adj, cursor, edge_src, e);

  k_fused<<<n / 32, blk, 0, stream>>>(pm_bf16, wbigP, bias_out, enc_bf16, litmean_bf, flags,
                                      attn_ln_g, attn_ln_b, gwP, twP, gate_b, trans_b,
                                      fus_ln_g, fus_ln_b, x0_bf, n);
  // layer 0 (gather fused)
  k_mp_mfma<<<n / 32, blk, 0, stream>>>(x0_bf, edge_src, row_ptr, mp0P, mp_b, mp_ln_g, mp_ln_b,
                                        nullptr, x1_bf, n);
  // layer 1
  k_mp_mfma<<<n / 32, blk, 0, stream>>>(x1_bf, edge_src, row_ptr, mp1P, mp_b + 256, mp_ln_g + 256,
                                        mp_ln_b + 256, (float*)d_out, nullptr, n);
}

// Round 9
// 634.827 us; speedup vs baseline: 1.1418x; 1.1418x over previous
//
#include <hip/hip_runtime.h>
#include <math.h>

#define H 256
#define L 32
#define HEADS 4
#define FEAT 7
#define LN_EPS 1e-5f

typedef __attribute__((ext_vector_type(8))) short bf16x8;
typedef __attribute__((ext_vector_type(4))) float f32x4;

__device__ __forceinline__ float wave_reduce_sum64(float v) {
#pragma unroll
  for (int m = 32; m >= 1; m >>= 1) v += __shfl_xor(v, m, 64);
  return v;
}

__device__ __forceinline__ short bf16rne(float f) {
  unsigned u = __float_as_uint(f);
  unsigned r = (u + 0x7FFFu + ((u >> 16) & 1u)) >> 16;
  return (short)r;
}

__device__ __forceinline__ float bf2f(short s) {
  return __uint_as_float(((unsigned)(unsigned short)s) << 16);
}

// ---------------- ONE prep kernel: all weight packing + folded mats + biases
// grid ranges: [0,32) w2P | [32,160) wqp | [160,288) wbig | [288,544) 4x pack512 | [544,548) bias_p | 548 bias_out
__global__ __launch_bounds__(256) void k_prep(
    const float* __restrict__ pe_w2, const float* __restrict__ aiw, const float* __restrict__ aow,
    const float* __restrict__ aib, const float* __restrict__ aob,
    const float* __restrict__ gate_w, const float* __restrict__ trans_w, const float* __restrict__ mp_w,
    short* __restrict__ w2P, short* __restrict__ wqpP, short* __restrict__ wbigP,
    short* __restrict__ gwP, short* __restrict__ twP, short* __restrict__ mp0P, short* __restrict__ mp1P,
    float* __restrict__ bias_p, float* __restrict__ bias_out) {
  const int bb = blockIdx.x;
  const int tid = threadIdx.x;
  if (bb < 32) {
    const int t = bb * 256 + tid;
    const int lane = t & 63;
    const int ks = (t >> 6) & 7;
    const int tcol = (t >> 6) >> 3;
    const int j = tcol * 16 + (lane & 15);
    const int k0 = ks * 32 + (lane >> 4) * 8;
    short v[8];
#pragma unroll
    for (int i = 0; i < 8; ++i) v[i] = bf16rne(pe_w2[(size_t)(k0 + i) * 256 + j]);
    *(int4*)&w2P[(size_t)t * 8] = *(int4*)v;
  } else if (bb < 160) {
    // Wqp[k, hc] = 0.125 * sum_d wq[k,h*64+d]*wk[c,h*64+d]  (N=1024, K=256)
    const int t = (bb - 32) * 256 + tid;
    const int lane = t & 63;
    const int ks = (t >> 6) & 7;
    const int tcol = t >> 9;
    const int col = tcol * 16 + (lane & 15);
    const int h = col >> 8, c = col & 255;
    const int k0 = ks * 32 + (lane >> 4) * 8;
    short v[8];
#pragma unroll
    for (int i = 0; i < 8; ++i) {
      const int k = k0 + i;
      float s = 0.f;
      for (int d = 0; d < 64; d += 4) {
        const float4 qa = *(const float4*)&aiw[(size_t)k * 768 + h * 64 + d];
        const float4 ka = *(const float4*)&aiw[(size_t)c * 768 + 256 + h * 64 + d];
        s = fmaf(qa.x, ka.x, fmaf(qa.y, ka.y, fmaf(qa.z, ka.z, fmaf(qa.w, ka.w, s))));
      }
      v[i] = bf16rne(0.125f * s);
    }
    *(int4*)&wqpP[(size_t)t * 8] = *(int4*)v;
  } else if (bb < 288) {
    // Wbig with K-reorder k' = c*4 + h: Wbig[k'][j] = sum_d wv[c,h*64+d]*aow[h*64+d][j]  (N=256, K=1024)
    const int t = (bb - 160) * 256 + tid;
    const int lane = t & 63;
    const int ks = (t >> 6) & 31;
    const int tcol = t >> 11;
    const int j = tcol * 16 + (lane & 15);
    const int k0 = ks * 32 + (lane >> 4) * 8;
    short v[8];
#pragma unroll
    for (int i = 0; i < 8; ++i) {
      const int k = k0 + i;
      const int c = k >> 2, h = k & 3;
      float s = 0.f;
      for (int d = 0; d < 64; ++d)
        s = fmaf(aiw[(size_t)c * 768 + 512 + h * 64 + d], aow[(size_t)(h * 64 + d) * 256 + j], s);
      v[i] = bf16rne(s);
    }
    *(int4*)&wbigP[(size_t)t * 8] = *(int4*)v;
  } else if (bb < 544) {
    const int sub = bb - 288;
    const int mi = sub >> 6;
    const float* W = (mi == 0) ? gate_w : (mi == 1) ? trans_w : (mi == 2) ? mp_w : (mp_w + 512 * 256);
    short* P = (mi == 0) ? gwP : (mi == 1) ? twP : (mi == 2) ? mp0P : mp1P;
    const int t = (sub & 63) * 256 + tid;
    const int lane = t & 63;
    const int ks = (t >> 6) & 15;
    const int tcol = (t >> 6) >> 4;
    const int j = tcol * 16 + (lane & 15);
    const int k0 = ks * 32 + (lane >> 4) * 8;
    short v[8];
#pragma unroll
    for (int i = 0; i < 8; ++i) v[i] = bf16rne(W[(size_t)(k0 + i) * 256 + j]);
    *(int4*)&P[(size_t)t * 8] = *(int4*)v;
  } else if (bb < 548) {
    const int col = (bb - 544) * 256 + tid;  // 1024
    const int h = col >> 8, c = col & 255;
    float s = 0.f;
    for (int d = 0; d < 64; ++d)
      s = fmaf(aib[h * 64 + d], aiw[(size_t)c * 768 + 256 + h * 64 + d], s);
    bias_p[col] = 0.125f * s;
  } else {
    const int j = tid;  // 256
    float s = aob[j];
    for (int e2 = 0; e2 < 256; ++e2) s = fmaf(aib[512 + e2], aow[(size_t)e2 * 256 + j], s);
    bias_out[j] = s;
  }
}

// ---------------- encoder (MFMA): h1 = relu(cf@w1+b1); enc = h1@w2+b2 (bf16); p = enc@Wqp + bias_p
__global__ __launch_bounds__(256) void k_enc_mfma(
    const float* __restrict__ cf, const float* __restrict__ pe_w1, const float* __restrict__ pe_b1,
    const short* __restrict__ w2P, const float* __restrict__ pe_b2,
    const short* __restrict__ wqpP, const float* __restrict__ bias_p,
    short* __restrict__ enc_bf16, short* __restrict__ p_bf16, int n) {
  __shared__ float cfs[32][FEAT];
  __shared__ short h1[32][264];
  __shared__ short encS[32][264];
  const int tid = threadIdx.x;
  const int lane = tid & 63, w = tid >> 6;
  const int n0 = blockIdx.x * 32;
  for (int idx = tid; idx < 32 * FEAT; idx += 256) cfs[idx / FEAT][idx % FEAT] = cf[(size_t)n0 * FEAT + idx];
  __syncthreads();
  {
    const int j = tid;
    float wv[FEAT];
#pragma unroll
    for (int f = 0; f < FEAT; ++f) wv[f] = pe_w1[f * H + j];
    const float b1v = pe_b1[j];
    for (int r = 0; r < 32; ++r) {
      float s = b1v;
#pragma unroll
      for (int f = 0; f < FEAT; ++f) s = fmaf(cfs[r][f], wv[f], s);
      h1[r][j] = bf16rne(fmaxf(s, 0.f));
    }
  }
  __syncthreads();
  const int arow = lane & 15;
  const int koff = (lane >> 4) * 8;
  {
    f32x4 acc[2][4];
#pragma unroll
    for (int rt = 0; rt < 2; ++rt)
#pragma unroll
      for (int ct = 0; ct < 4; ++ct) acc[rt][ct] = (f32x4)0.f;
#pragma unroll
    for (int ks = 0; ks < 8; ++ks) {
      const int k0 = ks * 32 + koff;
      const bf16x8 a0 = *(const bf16x8*)&h1[arow][k0];
      const bf16x8 a1 = *(const bf16x8*)&h1[16 + arow][k0];
#pragma unroll
      for (int ct = 0; ct < 4; ++ct) {
        const size_t fo = (((size_t)(w * 4 + ct) * 8 + ks) * 64 + lane) * 8;
        const bf16x8 b = *(const bf16x8*)&w2P[fo];
        acc[0][ct] = __builtin_amdgcn_mfma_f32_16x16x32_bf16(a0, b, acc[0][ct], 0, 0, 0);
        acc[1][ct] = __builtin_amdgcn_mfma_f32_16x16x32_bf16(a1, b, acc[1][ct], 0, 0, 0);
      }
    }
#pragma unroll
    for (int rt = 0; rt < 2; ++rt)
#pragma unroll
      for (int ct = 0; ct < 4; ++ct) {
        const int col = w * 64 + ct * 16 + (lane & 15);
        const float b2v = pe_b2[col];
#pragma unroll
        for (int i = 0; i < 4; ++i) {
          const int row = rt * 16 + (lane >> 4) * 4 + i;
          const short bv = bf16rne(acc[rt][ct][i] + b2v);
          encS[row][col] = bv;
          enc_bf16[(size_t)(n0 + row) * H + col] = bv;
        }
      }
  }
  __syncthreads();
#pragma unroll
  for (int chunk = 0; chunk < 2; ++chunk) {
    f32x4 acc[2][8];
#pragma unroll
    for (int rt = 0; rt < 2; ++rt)
#pragma unroll
      for (int c8 = 0; c8 < 8; ++c8) acc[rt][c8] = (f32x4)0.f;
#pragma unroll
    for (int ks = 0; ks < 8; ++ks) {
      const int k0 = ks * 32 + koff;
      const bf16x8 a0 = *(const bf16x8*)&encS[arow][k0];
      const bf16x8 a1 = *(const bf16x8*)&encS[16 + arow][k0];
#pragma unroll
      for (int c8 = 0; c8 < 8; ++c8) {
        const int tcol = w * 16 + chunk * 8 + c8;
        const size_t fo = (((size_t)tcol * 8 + ks) * 64 + lane) * 8;
        const bf16x8 b = *(const bf16x8*)&wqpP[fo];
        acc[0][c8] = __builtin_amdgcn_mfma_f32_16x16x32_bf16(a0, b, acc[0][c8], 0, 0, 0);
        acc[1][c8] = __builtin_amdgcn_mfma_f32_16x16x32_bf16(a1, b, acc[1][c8], 0, 0, 0);
      }
    }
#pragma unroll
    for (int rt = 0; rt < 2; ++rt)
#pragma unroll
      for (int c8 = 0; c8 < 8; ++c8) {
        const int col = w * 256 + (chunk * 8 + c8) * 16 + (lane & 15);
        const float bp = bias_p[col];
#pragma unroll
        for (int i = 0; i < 4; ++i) {
          const int row = rt * 16 + (lane >> 4) * 4 + i;
          p_bf16[(size_t)(n0 + row) * 1024 + col] = bf16rne(acc[rt][c8][i] + bp);
        }
      }
  }
}

// ---------------- per-clause attention: float4-staged bf16 lit, MFMA scores, coalesced m-store
// m layout: k' = c*4 + h  (matches Wbig packing)
__global__ __launch_bounds__(256) void k_attn(
    const float* __restrict__ lit, const int* __restrict__ mask,
    const short* __restrict__ p_in, short* __restrict__ m_out,
    short* __restrict__ litmean_bf, int* __restrict__ flags, int n) {
  __shared__ short lit_bs[32][264];
  __shared__ float attn_s[32][4];
  __shared__ int validS[32];
  __shared__ int nvalidS;
  const int j = threadIdx.x;
  const int nn = blockIdx.x;
  const float* litrow = lit + (size_t)nn * (L * H);
#pragma unroll
  for (int t = 0; t < 8; ++t) {
    const int idx = (t * 256 + j) << 2;
    const int r = idx >> 8, c = idx & 255;
    const float4 f = *(const float4*)&litrow[idx];
    short4 hv;
    hv.x = bf16rne(f.x); hv.y = bf16rne(f.y); hv.z = bf16rne(f.z); hv.w = bf16rne(f.w);
    *(short4*)&lit_bs[r][c] = hv;
  }
  if (j < 32) validS[j] = (mask[(size_t)nn * L + j] != 0) ? 1 : 0;
  __syncthreads();
  if (j == 0) {
    int c = 0;
#pragma unroll
    for (int l = 0; l < 32; ++l) c += validS[l];
    nvalidS = c;
  }
  __syncthreads();
  const int nvalid = nvalidS;
  const bool allm = (nvalid == 0);
  if (j < 64) {
    const int lane = j;
    f32x4 sc0 = (f32x4)0.f, sc1 = (f32x4)0.f;
    const int hh = lane & 3;
    const int krow = (lane >> 4) * 8;
    const short* prow = p_in + (size_t)nn * 1024 + hh * 256;
#pragma unroll
    for (int ks = 0; ks < 8; ++ks) {
      const bf16x8 a = *(const bf16x8*)&prow[ks * 32 + krow];
      const bf16x8 b0 = *(const bf16x8*)&lit_bs[lane & 15][ks * 32 + krow];
      const bf16x8 b1 = *(const bf16x8*)&lit_bs[16 + (lane & 15)][ks * 32 + krow];
      sc0 = __builtin_amdgcn_mfma_f32_16x16x32_bf16(a, b0, sc0, 0, 0, 0);
      sc1 = __builtin_amdgcn_mfma_f32_16x16x32_bf16(a, b1, sc1, 0, 0, 0);
    }
    if (lane < 16) {
      const int l0 = lane, l1 = 16 + lane;
      const bool ok0 = validS[l0] || (allm && l0 == 0);
      const bool ok1 = validS[l1] != 0;
#pragma unroll
      for (int i = 0; i < 4; ++i) {
        float s0 = ok0 ? sc0[i] : -INFINITY;
        float s1 = ok1 ? sc1[i] : -INFINITY;
        float mx = fmaxf(s0, s1);
#pragma unroll
        for (int m = 8; m >= 1; m >>= 1) mx = fmaxf(mx, __shfl_xor(mx, m, 16));
        float e0 = ok0 ? __expf(s0 - mx) : 0.f;
        float e1 = ok1 ? __expf(s1 - mx) : 0.f;
        float sm = e0 + e1;
#pragma unroll
        for (int m = 8; m >= 1; m >>= 1) sm += __shfl_xor(sm, m, 16);
        const float inv = 1.f / sm;
        attn_s[l0][i] = e0 * inv;
        attn_s[l1][i] = e1 * inv;
      }
    }
  }
  __syncthreads();
  {
    const float inv = 1.f / fmaxf((float)nvalid, 1.f);
    float lm = 0.f;
    float mm0 = 0.f, mm1 = 0.f, mm2 = 0.f, mm3 = 0.f;
#pragma unroll
    for (int l = 0; l < 32; ++l) {
      const float lv = bf2f(lit_bs[l][j]);
      if (validS[l]) lm += lv;
      const float4 av = *(const float4*)&attn_s[l][0];
      mm0 = fmaf(av.x, lv, mm0);
      mm1 = fmaf(av.y, lv, mm1);
      mm2 = fmaf(av.z, lv, mm2);
      mm3 = fmaf(av.w, lv, mm3);
    }
    litmean_bf[(size_t)nn * H + j] = bf16rne(lm * inv);
    short4 mv;
    mv.x = bf16rne(mm0); mv.y = bf16rne(mm1); mv.z = bf16rne(mm2); mv.w = bf16rne(mm3);
    *(short4*)&m_out[(size_t)nn * 1024 + j * 4] = mv;  // k' = j*4 + h
  }
  if (j == 0) flags[nn] = allm ? 1 : 0;
}

// ---------------- fused: ctx/out-proj GEMM (K'=1024) + LN1 + gate/trans GEMMs + fusion LN -> x0 bf16
__global__ __launch_bounds__(256) void k_fused(
    const short* __restrict__ m_bf16, const short* __restrict__ wbigP, const float* __restrict__ bias_out,
    const short* __restrict__ enc_bf16, const short* __restrict__ litmean_bf, const int* __restrict__ flags,
    const float* __restrict__ ag, const float* __restrict__ ab,
    const short* __restrict__ gwP, const short* __restrict__ twP,
    const float* __restrict__ gb, const float* __restrict__ tb,
    const float* __restrict__ fg, const float* __restrict__ fb,
    short* __restrict__ xout_bf, int n) {
  __shared__ short As[32][520];
  __shared__ float v_s[32][260];
  __shared__ float mu_s[32], sg_s[32];
  __shared__ int flagS[32];
  const int tid = threadIdx.x;
  const int lane = tid & 63, w = tid >> 6;
  const int n0 = blockIdx.x * 32;
  for (int q8 = tid; q8 < 32 * 32; q8 += 256) {
    const int idx = q8 << 3;
    const int r = idx >> 8, c = idx & 255;
    *(int4*)&As[r][256 + c] = *(const int4*)&enc_bf16[(size_t)(n0 + r) * H + c];
  }
  if (tid < 32) flagS[tid] = flags[n0 + tid];
  const int arow = lane & 15;
  const int koff = (lane >> 4) * 8;
  f32x4 acc[2][4];
#pragma unroll
  for (int rt = 0; rt < 2; ++rt)
#pragma unroll
    for (int ct = 0; ct < 4; ++ct) acc[rt][ct] = (f32x4)0.f;
#pragma unroll 8
  for (int ks = 0; ks < 32; ++ks) {
    const size_t abase = (size_t)(n0 + arow) * 1024 + ks * 32 + koff;
    const bf16x8 a0 = *(const bf16x8*)&m_bf16[abase];
    const bf16x8 a1 = *(const bf16x8*)&m_bf16[abase + 16 * 1024];
#pragma unroll
    for (int ct = 0; ct < 4; ++ct) {
      const size_t fo = (((size_t)(w * 4 + ct) * 32 + ks) * 64 + lane) * 8;
      const bf16x8 bw = *(const bf16x8*)&wbigP[fo];
      acc[0][ct] = __builtin_amdgcn_mfma_f32_16x16x32_bf16(a0, bw, acc[0][ct], 0, 0, 0);
      acc[1][ct] = __builtin_amdgcn_mfma_f32_16x16x32_bf16(a1, bw, acc[1][ct], 0, 0, 0);
    }
  }
  __syncthreads();
#pragma unroll
  for (int rt = 0; rt < 2; ++rt)
#pragma unroll
    for (int ct = 0; ct < 4; ++ct) {
      const int col = w * 64 + ct * 16 + (lane & 15);
      const float bo = bias_out[col];
#pragma unroll
      for (int i = 0; i < 4; ++i) {
        const int row = rt * 16 + (lane >> 4) * 4 + i;
        const float o = flagS[row] ? 0.f : (acc[rt][ct][i] + bo);
        v_s[row][col] = o + bf2f(As[row][256 + col]);
      }
    }
  __syncthreads();
  for (int r = w; r < 32; r += 4) {
    float ps = 0.f, pq = 0.f;
#pragma unroll
    for (int t = 0; t < 4; ++t) {
      float v = v_s[r][lane + 64 * t];
      ps += v;
      pq = fmaf(v, v, pq);
    }
    ps = wave_reduce_sum64(ps);
    pq = wave_reduce_sum64(pq);
    if (lane == 0) {
      float mu = ps * (1.f / H);
      mu_s[r] = mu;
      sg_s[r] = rsqrtf(pq * (1.f / H) - mu * mu + LN_EPS);
    }
  }
  __syncthreads();
  {
    const float agv = ag[tid], abv = ab[tid];
    for (int r = 0; r < 32; ++r) {
      const float val = (v_s[r][tid] - mu_s[r]) * sg_s[r] * agv + abv +
                        bf2f(litmean_bf[(size_t)(n0 + r) * H + tid]);
      As[r][tid] = bf16rne(val);
    }
  }
  __syncthreads();
  f32x4 accg[2][4], acct[2][4];
#pragma unroll
  for (int rt = 0; rt < 2; ++rt)
#pragma unroll
    for (int ct = 0; ct < 4; ++ct) { accg[rt][ct] = (f32x4)0.f; acct[rt][ct] = (f32x4)0.f; }
#pragma unroll 4
  for (int ks = 0; ks < 16; ++ks) {
    const int k0 = ks * 32 + koff;
    const bf16x8 a0 = *(const bf16x8*)&As[arow][k0];
    const bf16x8 a1 = *(const bf16x8*)&As[16 + arow][k0];
#pragma unroll
    for (int ct = 0; ct < 4; ++ct) {
      const size_t fo = (((size_t)(w * 4 + ct) * 16 + ks) * 64 + lane) * 8;
      const bf16x8 bg = *(const bf16x8*)&gwP[fo];
      const bf16x8 bt = *(const bf16x8*)&twP[fo];
      accg[0][ct] = __builtin_amdgcn_mfma_f32_16x16x32_bf16(a0, bg, accg[0][ct], 0, 0, 0);
      accg[1][ct] = __builtin_amdgcn_mfma_f32_16x16x32_bf16(a1, bg, accg[1][ct], 0, 0, 0);
      acct[0][ct] = __builtin_amdgcn_mfma_f32_16x16x32_bf16(a0, bt, acct[0][ct], 0, 0, 0);
      acct[1][ct] = __builtin_amdgcn_mfma_f32_16x16x32_bf16(a1, bt, acct[1][ct], 0, 0, 0);
    }
  }
#pragma unroll
  for (int rt = 0; rt < 2; ++rt)
#pragma unroll
    for (int ct = 0; ct < 4; ++ct) {
      const int col = w * 64 + ct * 16 + (lane & 15);
      const float gbv = gb[col], tbv = tb[col];
#pragma unroll
      for (int i = 0; i < 4; ++i) {
        const int rl = rt * 16 + (lane >> 4) * 4 + i;
        const float gate = 1.f / (1.f + __expf(-(accg[rt][ct][i] + gbv)));
        const float tr = acct[rt][ct][i] + tbv;
        const float a = bf2f(As[rl][col]);
        v_s[rl][col] = fmaf(gate, a - tr, tr);
      }
    }
  __syncthreads();
  for (int r = w; r < 32; r += 4) {
    float ps = 0.f, pq = 0.f;
#pragma unroll
    for (int t = 0; t < 4; ++t) {
      float v = v_s[r][lane + 64 * t];
      ps += v;
      pq = fmaf(v, v, pq);
    }
    ps = wave_reduce_sum64(ps);
    pq = wave_reduce_sum64(pq);
    if (lane == 0) {
      float mu = ps * (1.f / H);
      mu_s[r] = mu;
      sg_s[r] = rsqrtf(pq * (1.f / H) - mu * mu + LN_EPS);
    }
  }
  __syncthreads();
  {
    const float fgv = fg[tid], fbv = fb[tid];
    for (int r = 0; r < 32; ++r)
      xout_bf[(size_t)(n0 + r) * H + tid] = bf16rne((v_s[r][tid] - mu_s[r]) * sg_s[r] * fgv + fbv);
  }
}

// ---------------- mp layer via MFMA (bf16 in, bf16 residual): x' = LN(x + relu([x,agg]@w+b))
__global__ __launch_bounds__(256) void k_mp_mfma(
    const short* __restrict__ xin_bf, const short* __restrict__ agg_bf,
    const short* __restrict__ wP, const float* __restrict__ bias,
    const float* __restrict__ g, const float* __restrict__ b,
    float* __restrict__ xout_f32, short* __restrict__ xout_bf, int n) {
  __shared__ short As[32][520];
  __shared__ float v_s[32][260];
  __shared__ float mu_s[32], sg_s[32];
  const int tid = threadIdx.x;
  const int lane = tid & 63, w = tid >> 6;
  const int n0 = blockIdx.x * 32;
  for (int q8 = tid; q8 < 32 * 64; q8 += 256) {
    const int idx = q8 << 3;
    const int r = idx >> 9, c = idx & 511;
    const short* src = (c < H) ? &xin_bf[(size_t)(n0 + r) * H + c]
                               : &agg_bf[(size_t)(n0 + r) * H + (c - H)];
    *(int4*)&As[r][c] = *(const int4*)src;
  }
  __syncthreads();
  f32x4 acc[2][4];
#pragma unroll
  for (int rt = 0; rt < 2; ++rt)
#pragma unroll
    for (int ct = 0; ct < 4; ++ct) acc[rt][ct] = (f32x4)0.f;
  const int arow = lane & 15;
  const int koff = (lane >> 4) * 8;
#pragma unroll 4
  for (int ks = 0; ks < 16; ++ks) {
    const int k0 = ks * 32 + koff;
    const bf16x8 a0 = *(const bf16x8*)&As[arow][k0];
    const bf16x8 a1 = *(const bf16x8*)&As[16 + arow][k0];
#pragma unroll
    for (int ct = 0; ct < 4; ++ct) {
      const size_t fo = (((size_t)(w * 4 + ct) * 16 + ks) * 64 + lane) * 8;
      const bf16x8 bw = *(const bf16x8*)&wP[fo];
      acc[0][ct] = __builtin_amdgcn_mfma_f32_16x16x32_bf16(a0, bw, acc[0][ct], 0, 0, 0);
      acc[1][ct] = __builtin_amdgcn_mfma_f32_16x16x32_bf16(a1, bw, acc[1][ct], 0, 0, 0);
    }
  }
#pragma unroll
  for (int rt = 0; rt < 2; ++rt)
#pragma unroll
    for (int ct = 0; ct < 4; ++ct) {
      const int col = w * 64 + ct * 16 + (lane & 15);
      const float bsv = bias[col];
#pragma unroll
      for (int i = 0; i < 4; ++i) {
        const int rl = rt * 16 + (lane >> 4) * 4 + i;
        const float u = fmaxf(acc[rt][ct][i] + bsv, 0.f);
        v_s[rl][col] = bf2f(As[rl][col]) + u;
      }
    }
  __syncthreads();
  for (int r = w; r < 32; r += 4) {
    float ps = 0.f, pq = 0.f;
#pragma unroll
    for (int t = 0; t < 4; ++t) {
      float v = v_s[r][lane + 64 * t];
      ps += v;
      pq = fmaf(v, v, pq);
    }
    ps = wave_reduce_sum64(ps);
    pq = wave_reduce_sum64(pq);
    if (lane == 0) {
      float mu = ps * (1.f / H);
      mu_s[r] = mu;
      sg_s[r] = rsqrtf(pq * (1.f / H) - mu * mu + LN_EPS);
    }
  }
  __syncthreads();
  const float gv = g[tid], bv = b[tid];
  for (int r = 0; r < 32; ++r) {
    const float val = (v_s[r][tid] - mu_s[r]) * sg_s[r] * gv + bv;
    if (xout_f32) xout_f32[(size_t)(n0 + r) * H + tid] = val;
    if (xout_bf) xout_bf[(size_t)(n0 + r) * H + tid] = bf16rne(val);
  }
}

// ---------------- CSR build
__global__ void k_zero_int(int* __restrict__ p, int count) {
  int i = blockIdx.x * blockDim.x + threadIdx.x;
  if (i < count) p[i] = 0;
}

__global__ void k_hist(const int* __restrict__ dst, int* __restrict__ hist, int e) {
  int i = blockIdx.x * blockDim.x + threadIdx.x;
  if (i < e) atomicAdd(&hist[dst[i]], 1);
}

__global__ __launch_bounds__(1024) void k_scan(
    const int* __restrict__ hist, int* __restrict__ row_ptr, int* __restrict__ cursor, int n, int e) {
  __shared__ int part[1024];
  const int t = threadIdx.x;
  const int chunk = (n + 1023) / 1024;
  const int lo = t * chunk;
  const int hi = min(lo + chunk, n);
  int s = 0;
  for (int i = lo; i < hi; ++i) s += hist[i];
  part[t] = s;
  __syncthreads();
  for (int d = 1; d < 1024; d <<= 1) {
    int v = (t >= d) ? part[t - d] : 0;
    __syncthreads();
    part[t] += v;
    __syncthreads();
  }
  int run = (t > 0) ? part[t - 1] : 0;
  for (int i = lo; i < hi; ++i) {
    row_ptr[i] = run;
    cursor[i] = run;
    run += hist[i];
  }
  if (t == 1023) row_ptr[n] = e;
}

__global__ void k_fill(const int* __restrict__ adj, int* __restrict__ cursor,
                       int* __restrict__ edge_src, int e) {
  int i = blockIdx.x * blockDim.x + threadIdx.x;
  if (i < e) {
    int s = adj[i], d = adj[e + i];
    int pos = atomicAdd(&cursor[d], 1);
    edge_src[pos] = s;
  }
}

// ---------------- gather (bf16), one wave per dst row, unroll-4 for MLP
__global__ __launch_bounds__(256) void k_gather(
    const short* __restrict__ x, const int* __restrict__ edge_src, const int* __restrict__ row_ptr,
    short* __restrict__ agg, int n) {
  const int wid = threadIdx.x >> 6;
  const int lane = threadIdx.x & 63;
  const int d = blockIdx.x * 4 + wid;
  if (d >= n) return;
  const int beg = row_ptr[d], end = row_ptr[d + 1];
  float4 acc = {0.f, 0.f, 0.f, 0.f};
  int i = beg;
  for (; i + 4 <= end; i += 4) {
    const int s0 = edge_src[i], s1 = edge_src[i + 1], s2 = edge_src[i + 2], s3 = edge_src[i + 3];
    const short4 v0 = *(const short4*)(x + (size_t)s0 * H + lane * 4);
    const short4 v1 = *(const short4*)(x + (size_t)s1 * H + lane * 4);
    const short4 v2 = *(const short4*)(x + (size_t)s2 * H + lane * 4);
    const short4 v3 = *(const short4*)(x + (size_t)s3 * H + lane * 4);
    acc.x += bf2f(v0.x) + bf2f(v1.x) + bf2f(v2.x) + bf2f(v3.x);
    acc.y += bf2f(v0.y) + bf2f(v1.y) + bf2f(v2.y) + bf2f(v3.y);
    acc.z += bf2f(v0.z) + bf2f(v1.z) + bf2f(v2.z) + bf2f(v3.z);
    acc.w += bf2f(v0.w) + bf2f(v1.w) + bf2f(v2.w) + bf2f(v3.w);
  }
  for (; i < end; ++i) {
    const int s = edge_src[i];
    const short4 v = *(const short4*)(x + (size_t)s * H + lane * 4);
    acc.x += bf2f(v.x); acc.y += bf2f(v.y); acc.z += bf2f(v.z); acc.w += bf2f(v.w);
  }
  const float inv = 1.f / fmaxf((float)(end - beg), 1.f);
  short4 o;
  o.x = bf16rne(acc.x * inv); o.y = bf16rne(acc.y * inv);
  o.z = bf16rne(acc.z * inv); o.w = bf16rne(acc.w * inv);
  *(short4*)(agg + (size_t)d * H + lane * 4) = o;
}

extern "C" void kernel_launch(void* const* d_in, const int* in_sizes, int n_in,
                              void* d_out, int out_size, void* d_ws, size_t ws_size,
                              hipStream_t stream) {
  const float* lit = (const float*)d_in[0];
  const float* cf = (const float*)d_in[1];
  const int* mask = (const int*)d_in[2];
  const int* adj = (const int*)d_in[3];
  const float* pe_w1 = (const float*)d_in[4];
  const float* pe_b1 = (const float*)d_in[5];
  const float* pe_w2 = (const float*)d_in[6];
  const float* pe_b2 = (const float*)d_in[7];
  const float* aiw = (const float*)d_in[8];
  const float* aib = (const float*)d_in[9];
  const float* aow = (const float*)d_in[10];
  const float* aob = (const float*)d_in[11];
  const float* attn_ln_g = (const float*)d_in[12];
  const float* attn_ln_b = (const float*)d_in[13];
  const float* gate_w = (const float*)d_in[14];
  const float* gate_b = (const float*)d_in[15];
  const float* trans_w = (const float*)d_in[16];
  const float* trans_b = (const float*)d_in[17];
  const float* fus_ln_g = (const float*)d_in[18];
  const float* fus_ln_b = (const float*)d_in[19];
  const float* mp_w = (const float*)d_in[20];
  const float* mp_b = (const float*)d_in[21];
  const float* mp_ln_g = (const float*)d_in[22];
  const float* mp_ln_b = (const float*)d_in[23];

  const int n = in_sizes[1] / FEAT;   // 20000
  const int e = in_sizes[3] / 2;      // 640000

  float* ws = (float*)d_ws;
  size_t off = 0;
  short* enc_bf16 = (short*)(ws + off); off += (size_t)n * 128;
  short* pm_bf16 = (short*)(ws + off); off += (size_t)n * 512;   // p then m (in-place)
  short* litmean_bf = (short*)(ws + off); off += (size_t)n * 128;
  short* x0_bf = (short*)(ws + off); off += (size_t)n * 128;
  short* x1_bf = (short*)(ws + off); off += (size_t)n * 128;
  short* agg_bf = (short*)(ws + off); off += (size_t)n * 128;
  int* flags = (int*)(ws + off); off += n;
  int* hist = (int*)(ws + off); off += n;
  int* row_ptr = (int*)(ws + off); off += n + 2;
  int* cursor = (int*)(ws + off); off += n;
  int* edge_src = (int*)(ws + off); off += e;
  short* w2P = (short*)(ws + off); off += 256 * 256 / 2;
  short* wqpP = (short*)(ws + off); off += 256 * 1024 / 2;
  short* wbigP = (short*)(ws + off); off += 1024 * 256 / 2;
  short* gwP = (short*)(ws + off); off += 512 * 256 / 2;
  short* twP = (short*)(ws + off); off += 512 * 256 / 2;
  short* mp0P = (short*)(ws + off); off += 512 * 256 / 2;
  short* mp1P = (short*)(ws + off); off += 512 * 256 / 2;
  float* bias_p = ws + off; off += 1024;
  float* bias_out = ws + off; off += 256;

  dim3 blk(256);
  k_prep<<<549, blk, 0, stream>>>(pe_w2, aiw, aow, aib, aob, gate_w, trans_w, mp_w,
                                  w2P, wqpP, wbigP, gwP, twP, mp0P, mp1P, bias_p, bias_out);

  k_enc_mfma<<<n / 32, blk, 0, stream>>>(cf, pe_w1, pe_b1, w2P, pe_b2, wqpP, bias_p, enc_bf16, pm_bf16, n);
  k_attn<<<n, blk, 0, stream>>>(lit, mask, pm_bf16, pm_bf16, litmean_bf, flags, n);

  // CSR build
  k_zero_int<<<(n + 255) / 256, blk, 0, stream>>>(hist, n);
  k_hist<<<(e + 255) / 256, blk, 0, stream>>>(adj + e, hist, e);
  k_scan<<<1, 1024, 0, stream>>>(hist, row_ptr, cursor, n, e);
  k_fill<<<(e + 255) / 256, blk, 0, stream>>>(adj, cursor, edge_src, e);

  k_fused<<<n / 32, blk, 0, stream>>>(pm_bf16, wbigP, bias_out, enc_bf16, litmean_bf, flags,
                                      attn_ln_g, attn_ln_b, gwP, twP, gate_b, trans_b,
                                      fus_ln_g, fus_ln_b, x0_bf, n);
  // layer 0
  k_gather<<<(n + 3) / 4, blk, 0, stream>>>(x0_bf, edge_src, row_ptr, agg_bf, n);
  k_mp_mfma<<<n / 32, blk, 0, stream>>>(x0_bf, agg_bf, mp0P, mp_b, mp_ln_g, mp_ln_b,
                                        nullptr, x1_bf, n);
  // layer 1
  k_gather<<<(n + 3) / 4, blk, 0, stream>>>(x1_bf, edge_src, row_ptr, agg_bf, n);
  k_mp_mfma<<<n / 32, blk, 0, stream>>>(x1_bf, agg_bf, mp1P, mp_b + 256, mp_ln_g + 256,
                                        mp_ln_b + 256, (float*)d_out, nullptr, n);
}

// Round 11
// 579.951 us; speedup vs baseline: 1.2498x; 1.0946x over previous
//
#include <hip/hip_runtime.h>
#include <math.h>

#define H 256
#define L 32
#define HEADS 4
#define FEAT 7
#define LN_EPS 1e-5f

typedef __attribute__((ext_vector_type(8))) short bf16x8;
typedef __attribute__((ext_vector_type(4))) float f32x4;
typedef __attribute__((ext_vector_type(4))) float fvec4;  // native vector for nontemporal builtin

__device__ __forceinline__ float wave_reduce_sum64(float v) {
#pragma unroll
  for (int m = 32; m >= 1; m >>= 1) v += __shfl_xor(v, m, 64);
  return v;
}

__device__ __forceinline__ short bf16rne(float f) {
  unsigned u = __float_as_uint(f);
  unsigned r = (u + 0x7FFFu + ((u >> 16) & 1u)) >> 16;
  return (short)r;
}

__device__ __forceinline__ float bf2f(short s) {
  return __uint_as_float(((unsigned)(unsigned short)s) << 16);
}

// ---------------- ONE prep kernel: all weight packing + folded mats + biases + hist zero
// grid: [0,32) w2P | [32,160) wqp | [160,288) wbig | [288,544) 4x pack512 | [544,548) bias_p | 548 bias_out | [549,...) hist=0
__global__ __launch_bounds__(256) void k_prep(
    const float* __restrict__ pe_w2, const float* __restrict__ aiw, const float* __restrict__ aow,
    const float* __restrict__ aib, const float* __restrict__ aob,
    const float* __restrict__ gate_w, const float* __restrict__ trans_w, const float* __restrict__ mp_w,
    short* __restrict__ w2P, short* __restrict__ wqpP, short* __restrict__ wbigP,
    short* __restrict__ gwP, short* __restrict__ twP, short* __restrict__ mp0P, short* __restrict__ mp1P,
    float* __restrict__ bias_p, float* __restrict__ bias_out, int* __restrict__ hist, int n) {
  const int bb = blockIdx.x;
  const int tid = threadIdx.x;
  if (bb < 32) {
    const int t = bb * 256 + tid;
    const int lane = t & 63;
    const int ks = (t >> 6) & 7;
    const int tcol = (t >> 6) >> 3;
    const int j = tcol * 16 + (lane & 15);
    const int k0 = ks * 32 + (lane >> 4) * 8;
    short v[8];
#pragma unroll
    for (int i = 0; i < 8; ++i) v[i] = bf16rne(pe_w2[(size_t)(k0 + i) * 256 + j]);
    *(int4*)&w2P[(size_t)t * 8] = *(int4*)v;
  } else if (bb < 160) {
    // Wqp[k, hc] = 0.125 * sum_d wq[k,h*64+d]*wk[c,h*64+d]  (N=1024, K=256)
    const int t = (bb - 32) * 256 + tid;
    const int lane = t & 63;
    const int ks = (t >> 6) & 7;
    const int tcol = t >> 9;
    const int col = tcol * 16 + (lane & 15);
    const int h = col >> 8, c = col & 255;
    const int k0 = ks * 32 + (lane >> 4) * 8;
    short v[8];
#pragma unroll
    for (int i = 0; i < 8; ++i) {
      const int k = k0 + i;
      float s = 0.f;
      for (int d = 0; d < 64; d += 4) {
        const float4 qa = *(const float4*)&aiw[(size_t)k * 768 + h * 64 + d];
        const float4 ka = *(const float4*)&aiw[(size_t)c * 768 + 256 + h * 64 + d];
        s = fmaf(qa.x, ka.x, fmaf(qa.y, ka.y, fmaf(qa.z, ka.z, fmaf(qa.w, ka.w, s))));
      }
      v[i] = bf16rne(0.125f * s);
    }
    *(int4*)&wqpP[(size_t)t * 8] = *(int4*)v;
  } else if (bb < 288) {
    // Wbig with K-reorder k' = c*4 + h: Wbig[k'][j] = sum_d wv[c,h*64+d]*aow[h*64+d][j]  (N=256, K=1024)
    const int t = (bb - 160) * 256 + tid;
    const int lane = t & 63;
    const int ks = (t >> 6) & 31;
    const int tcol = t >> 11;
    const int j = tcol * 16 + (lane & 15);
    const int k0 = ks * 32 + (lane >> 4) * 8;
    short v[8];
#pragma unroll
    for (int i = 0; i < 8; ++i) {
      const int k = k0 + i;
      const int c = k >> 2, h = k & 3;
      float s = 0.f;
      for (int d = 0; d < 64; ++d)
        s = fmaf(aiw[(size_t)c * 768 + 512 + h * 64 + d], aow[(size_t)(h * 64 + d) * 256 + j], s);
      v[i] = bf16rne(s);
    }
    *(int4*)&wbigP[(size_t)t * 8] = *(int4*)v;
  } else if (bb < 544) {
    const int sub = bb - 288;
    const int mi = sub >> 6;
    const float* W = (mi == 0) ? gate_w : (mi == 1) ? trans_w : (mi == 2) ? mp_w : (mp_w + 512 * 256);
    short* P = (mi == 0) ? gwP : (mi == 1) ? twP : (mi == 2) ? mp0P : mp1P;
    const int t = (sub & 63) * 256 + tid;
    const int lane = t & 63;
    const int ks = (t >> 6) & 15;
    const int tcol = (t >> 6) >> 4;
    const int j = tcol * 16 + (lane & 15);
    const int k0 = ks * 32 + (lane >> 4) * 8;
    short v[8];
#pragma unroll
    for (int i = 0; i < 8; ++i) v[i] = bf16rne(W[(size_t)(k0 + i) * 256 + j]);
    *(int4*)&P[(size_t)t * 8] = *(int4*)v;
  } else if (bb < 548) {
    const int col = (bb - 544) * 256 + tid;  // 1024
    const int h = col >> 8, c = col & 255;
    float s = 0.f;
    for (int d = 0; d < 64; ++d)
      s = fmaf(aib[h * 64 + d], aiw[(size_t)c * 768 + 256 + h * 64 + d], s);
    bias_p[col] = 0.125f * s;
  } else if (bb == 548) {
    const int j = tid;  // 256
    float s = aob[j];
    for (int e2 = 0; e2 < 256; ++e2) s = fmaf(aib[512 + e2], aow[(size_t)e2 * 256 + j], s);
    bias_out[j] = s;
  } else {
    const int i = (bb - 549) * 256 + tid;
    if (i < n) hist[i] = 0;
  }
}

// ---------------- encoder (MFMA): h1 = relu(cf@w1+b1); enc = h1@w2+b2 (bf16); p = enc@Wqp + bias_p
__global__ __launch_bounds__(256) void k_enc_mfma(
    const float* __restrict__ cf, const float* __restrict__ pe_w1, const float* __restrict__ pe_b1,
    const short* __restrict__ w2P, const float* __restrict__ pe_b2,
    const short* __restrict__ wqpP, const float* __restrict__ bias_p,
    short* __restrict__ enc_bf16, short* __restrict__ p_bf16, int n) {
  __shared__ float cfs[32][FEAT];
  __shared__ short h1[32][264];
  __shared__ short encS[32][264];
  const int tid = threadIdx.x;
  const int lane = tid & 63, w = tid >> 6;
  const int n0 = blockIdx.x * 32;
  for (int idx = tid; idx < 32 * FEAT; idx += 256) cfs[idx / FEAT][idx % FEAT] = cf[(size_t)n0 * FEAT + idx];
  __syncthreads();
  {
    const int j = tid;
    float wv[FEAT];
#pragma unroll
    for (int f = 0; f < FEAT; ++f) wv[f] = pe_w1[f * H + j];
    const float b1v = pe_b1[j];
    for (int r = 0; r < 32; ++r) {
      float s = b1v;
#pragma unroll
      for (int f = 0; f < FEAT; ++f) s = fmaf(cfs[r][f], wv[f], s);
      h1[r][j] = bf16rne(fmaxf(s, 0.f));
    }
  }
  __syncthreads();
  const int arow = lane & 15;
  const int koff = (lane >> 4) * 8;
  {
    f32x4 acc[2][4];
#pragma unroll
    for (int rt = 0; rt < 2; ++rt)
#pragma unroll
      for (int ct = 0; ct < 4; ++ct) acc[rt][ct] = (f32x4)0.f;
#pragma unroll
    for (int ks = 0; ks < 8; ++ks) {
      const int k0 = ks * 32 + koff;
      const bf16x8 a0 = *(const bf16x8*)&h1[arow][k0];
      const bf16x8 a1 = *(const bf16x8*)&h1[16 + arow][k0];
#pragma unroll
      for (int ct = 0; ct < 4; ++ct) {
        const size_t fo = (((size_t)(w * 4 + ct) * 8 + ks) * 64 + lane) * 8;
        const bf16x8 b = *(const bf16x8*)&w2P[fo];
        acc[0][ct] = __builtin_amdgcn_mfma_f32_16x16x32_bf16(a0, b, acc[0][ct], 0, 0, 0);
        acc[1][ct] = __builtin_amdgcn_mfma_f32_16x16x32_bf16(a1, b, acc[1][ct], 0, 0, 0);
      }
    }
#pragma unroll
    for (int rt = 0; rt < 2; ++rt)
#pragma unroll
      for (int ct = 0; ct < 4; ++ct) {
        const int col = w * 64 + ct * 16 + (lane & 15);
        const float b2v = pe_b2[col];
#pragma unroll
        for (int i = 0; i < 4; ++i) {
          const int row = rt * 16 + (lane >> 4) * 4 + i;
          const short bv = bf16rne(acc[rt][ct][i] + b2v);
          encS[row][col] = bv;
          enc_bf16[(size_t)(n0 + row) * H + col] = bv;
        }
      }
  }
  __syncthreads();
#pragma unroll
  for (int chunk = 0; chunk < 2; ++chunk) {
    f32x4 acc[2][8];
#pragma unroll
    for (int rt = 0; rt < 2; ++rt)
#pragma unroll
      for (int c8 = 0; c8 < 8; ++c8) acc[rt][c8] = (f32x4)0.f;
#pragma unroll
    for (int ks = 0; ks < 8; ++ks) {
      const int k0 = ks * 32 + koff;
      const bf16x8 a0 = *(const bf16x8*)&encS[arow][k0];
      const bf16x8 a1 = *(const bf16x8*)&encS[16 + arow][k0];
#pragma unroll
      for (int c8 = 0; c8 < 8; ++c8) {
        const int tcol = w * 16 + chunk * 8 + c8;
        const size_t fo = (((size_t)tcol * 8 + ks) * 64 + lane) * 8;
        const bf16x8 b = *(const bf16x8*)&wqpP[fo];
        acc[0][c8] = __builtin_amdgcn_mfma_f32_16x16x32_bf16(a0, b, acc[0][c8], 0, 0, 0);
        acc[1][c8] = __builtin_amdgcn_mfma_f32_16x16x32_bf16(a1, b, acc[1][c8], 0, 0, 0);
      }
    }
#pragma unroll
    for (int rt = 0; rt < 2; ++rt)
#pragma unroll
      for (int c8 = 0; c8 < 8; ++c8) {
        const int col = w * 256 + (chunk * 8 + c8) * 16 + (lane & 15);
        const float bp = bias_p[col];
#pragma unroll
        for (int i = 0; i < 4; ++i) {
          const int row = rt * 16 + (lane >> 4) * 4 + i;
          p_bf16[(size_t)(n0 + row) * 1024 + col] = bf16rne(acc[rt][c8][i] + bp);
        }
      }
  }
}

// ---------------- per-clause attention: nontemporal float4-staged bf16 lit, MFMA scores, coalesced m-store
// m layout: k' = c*4 + h  (matches Wbig packing)
__global__ __launch_bounds__(256) void k_attn(
    const float* __restrict__ lit, const int* __restrict__ mask,
    const short* __restrict__ p_in, short* __restrict__ m_out,
    short* __restrict__ litmean_bf, int* __restrict__ flags, int n) {
  __shared__ short lit_bs[32][264];
  __shared__ float attn_s[32][4];
  __shared__ int validS[32];
  __shared__ int nvalidS;
  const int j = threadIdx.x;
  const int nn = blockIdx.x;
  const fvec4* litrow4 = (const fvec4*)(lit + (size_t)nn * (L * H));
#pragma unroll
  for (int t = 0; t < 8; ++t) {
    const int q = t * 256 + j;
    const int idx = q << 2;
    const int r = idx >> 8, c = idx & 255;
    const fvec4 f = __builtin_nontemporal_load(&litrow4[q]);
    short4 hv;
    hv.x = bf16rne(f.x); hv.y = bf16rne(f.y); hv.z = bf16rne(f.z); hv.w = bf16rne(f.w);
    *(short4*)&lit_bs[r][c] = hv;
  }
  if (j < 32) validS[j] = (mask[(size_t)nn * L + j] != 0) ? 1 : 0;
  __syncthreads();
  if (j == 0) {
    int c = 0;
#pragma unroll
    for (int l = 0; l < 32; ++l) c += validS[l];
    nvalidS = c;
  }
  __syncthreads();
  const int nvalid = nvalidS;
  const bool allm = (nvalid == 0);
  if (j < 64) {
    const int lane = j;
    f32x4 sc0 = (f32x4)0.f, sc1 = (f32x4)0.f;
    const int hh = lane & 3;
    const int krow = (lane >> 4) * 8;
    const short* prow = p_in + (size_t)nn * 1024 + hh * 256;
#pragma unroll
    for (int ks = 0; ks < 8; ++ks) {
      const bf16x8 a = *(const bf16x8*)&prow[ks * 32 + krow];
      const bf16x8 b0 = *(const bf16x8*)&lit_bs[lane & 15][ks * 32 + krow];
      const bf16x8 b1 = *(const bf16x8*)&lit_bs[16 + (lane & 15)][ks * 32 + krow];
      sc0 = __builtin_amdgcn_mfma_f32_16x16x32_bf16(a, b0, sc0, 0, 0, 0);
      sc1 = __builtin_amdgcn_mfma_f32_16x16x32_bf16(a, b1, sc1, 0, 0, 0);
    }
    if (lane < 16) {
      const int l0 = lane, l1 = 16 + lane;
      const bool ok0 = validS[l0] || (allm && l0 == 0);
      const bool ok1 = validS[l1] != 0;
#pragma unroll
      for (int i = 0; i < 4; ++i) {
        float s0 = ok0 ? sc0[i] : -INFINITY;
        float s1 = ok1 ? sc1[i] : -INFINITY;
        float mx = fmaxf(s0, s1);
#pragma unroll
        for (int m = 8; m >= 1; m >>= 1) mx = fmaxf(mx, __shfl_xor(mx, m, 16));
        float e0 = ok0 ? __expf(s0 - mx) : 0.f;
        float e1 = ok1 ? __expf(s1 - mx) : 0.f;
        float sm = e0 + e1;
#pragma unroll
        for (int m = 8; m >= 1; m >>= 1) sm += __shfl_xor(sm, m, 16);
        const float inv = 1.f / sm;
        attn_s[l0][i] = e0 * inv;
        attn_s[l1][i] = e1 * inv;
      }
    }
  }
  __syncthreads();
  {
    const float inv = 1.f / fmaxf((float)nvalid, 1.f);
    float lm = 0.f;
    float mm0 = 0.f, mm1 = 0.f, mm2 = 0.f, mm3 = 0.f;
#pragma unroll
    for (int l = 0; l < 32; ++l) {
      const float lv = bf2f(lit_bs[l][j]);
      if (validS[l]) lm += lv;
      const float4 av = *(const float4*)&attn_s[l][0];
      mm0 = fmaf(av.x, lv, mm0);
      mm1 = fmaf(av.y, lv, mm1);
      mm2 = fmaf(av.z, lv, mm2);
      mm3 = fmaf(av.w, lv, mm3);
    }
    litmean_bf[(size_t)nn * H + j] = bf16rne(lm * inv);
    short4 mv;
    mv.x = bf16rne(mm0); mv.y = bf16rne(mm1); mv.z = bf16rne(mm2); mv.w = bf16rne(mm3);
    *(short4*)&m_out[(size_t)nn * 1024 + j * 4] = mv;  // k' = j*4 + h
  }
  if (j == 0) flags[nn] = allm ? 1 : 0;
}

// ---------------- fused: ctx/out-proj GEMM (K'=1024) + LN1 + gate/trans GEMMs + fusion LN -> x0 bf16
__global__ __launch_bounds__(256) void k_fused(
    const short* __restrict__ m_bf16, const short* __restrict__ wbigP, const float* __restrict__ bias_out,
    const short* __restrict__ enc_bf16, const short* __restrict__ litmean_bf, const int* __restrict__ flags,
    const float* __restrict__ ag, const float* __restrict__ ab,
    const short* __restrict__ gwP, const short* __restrict__ twP,
    const float* __restrict__ gb, const float* __restrict__ tb,
    const float* __restrict__ fg, const float* __restrict__ fb,
    short* __restrict__ xout_bf, int n) {
  __shared__ short As[32][520];
  __shared__ float v_s[32][260];
  __shared__ float mu_s[32], sg_s[32];
  __shared__ int flagS[32];
  const int tid = threadIdx.x;
  const int lane = tid & 63, w = tid >> 6;
  const int n0 = blockIdx.x * 32;
  for (int q8 = tid; q8 < 32 * 32; q8 += 256) {
    const int idx = q8 << 3;
    const int r = idx >> 8, c = idx & 255;
    *(int4*)&As[r][256 + c] = *(const int4*)&enc_bf16[(size_t)(n0 + r) * H + c];
  }
  if (tid < 32) flagS[tid] = flags[n0 + tid];
  const int arow = lane & 15;
  const int koff = (lane >> 4) * 8;
  f32x4 acc[2][4];
#pragma unroll
  for (int rt = 0; rt < 2; ++rt)
#pragma unroll
    for (int ct = 0; ct < 4; ++ct) acc[rt][ct] = (f32x4)0.f;
#pragma unroll 8
  for (int ks = 0; ks < 32; ++ks) {
    const size_t abase = (size_t)(n0 + arow) * 1024 + ks * 32 + koff;
    const bf16x8 a0 = *(const bf16x8*)&m_bf16[abase];
    const bf16x8 a1 = *(const bf16x8*)&m_bf16[abase + 16 * 1024];
#pragma unroll
    for (int ct = 0; ct < 4; ++ct) {
      const size_t fo = (((size_t)(w * 4 + ct) * 32 + ks) * 64 + lane) * 8;
      const bf16x8 bw = *(const bf16x8*)&wbigP[fo];
      acc[0][ct] = __builtin_amdgcn_mfma_f32_16x16x32_bf16(a0, bw, acc[0][ct], 0, 0, 0);
      acc[1][ct] = __builtin_amdgcn_mfma_f32_16x16x32_bf16(a1, bw, acc[1][ct], 0, 0, 0);
    }
  }
  __syncthreads();
#pragma unroll
  for (int rt = 0; rt < 2; ++rt)
#pragma unroll
    for (int ct = 0; ct < 4; ++ct) {
      const int col = w * 64 + ct * 16 + (lane & 15);
      const float bo = bias_out[col];
#pragma unroll
      for (int i = 0; i < 4; ++i) {
        const int row = rt * 16 + (lane >> 4) * 4 + i;
        const float o = flagS[row] ? 0.f : (acc[rt][ct][i] + bo);
        v_s[row][col] = o + bf2f(As[row][256 + col]);
      }
    }
  __syncthreads();
  for (int r = w; r < 32; r += 4) {
    float ps = 0.f, pq = 0.f;
#pragma unroll
    for (int t = 0; t < 4; ++t) {
      float v = v_s[r][lane + 64 * t];
      ps += v;
      pq = fmaf(v, v, pq);
    }
    ps = wave_reduce_sum64(ps);
    pq = wave_reduce_sum64(pq);
    if (lane == 0) {
      float mu = ps * (1.f / H);
      mu_s[r] = mu;
      sg_s[r] = rsqrtf(pq * (1.f / H) - mu * mu + LN_EPS);
    }
  }
  __syncthreads();
  {
    const float agv = ag[tid], abv = ab[tid];
    for (int r = 0; r < 32; ++r) {
      const float val = (v_s[r][tid] - mu_s[r]) * sg_s[r] * agv + abv +
                        bf2f(litmean_bf[(size_t)(n0 + r) * H + tid]);
      As[r][tid] = bf16rne(val);
    }
  }
  __syncthreads();
  f32x4 accg[2][4], acct[2][4];
#pragma unroll
  for (int rt = 0; rt < 2; ++rt)
#pragma unroll
    for (int ct = 0; ct < 4; ++ct) { accg[rt][ct] = (f32x4)0.f; acct[rt][ct] = (f32x4)0.f; }
#pragma unroll 4
  for (int ks = 0; ks < 16; ++ks) {
    const int k0 = ks * 32 + koff;
    const bf16x8 a0 = *(const bf16x8*)&As[arow][k0];
    const bf16x8 a1 = *(const bf16x8*)&As[16 + arow][k0];
#pragma unroll
    for (int ct = 0; ct < 4; ++ct) {
      const size_t fo = (((size_t)(w * 4 + ct) * 16 + ks) * 64 + lane) * 8;
      const bf16x8 bg = *(const bf16x8*)&gwP[fo];
      const bf16x8 bt = *(const bf16x8*)&twP[fo];
      accg[0][ct] = __builtin_amdgcn_mfma_f32_16x16x32_bf16(a0, bg, accg[0][ct], 0, 0, 0);
      accg[1][ct] = __builtin_amdgcn_mfma_f32_16x16x32_bf16(a1, bg, accg[1][ct], 0, 0, 0);
      acct[0][ct] = __builtin_amdgcn_mfma_f32_16x16x32_bf16(a0, bt, acct[0][ct], 0, 0, 0);
      acct[1][ct] = __builtin_amdgcn_mfma_f32_16x16x32_bf16(a1, bt, acct[1][ct], 0, 0, 0);
    }
  }
#pragma unroll
  for (int rt = 0; rt < 2; ++rt)
#pragma unroll
    for (int ct = 0; ct < 4; ++ct) {
      const int col = w * 64 + ct * 16 + (lane & 15);
      const float gbv = gb[col], tbv = tb[col];
#pragma unroll
      for (int i = 0; i < 4; ++i) {
        const int rl = rt * 16 + (lane >> 4) * 4 + i;
        const float gate = 1.f / (1.f + __expf(-(accg[rt][ct][i] + gbv)));
        const float tr = acct[rt][ct][i] + tbv;
        const float a = bf2f(As[rl][col]);
        v_s[rl][col] = fmaf(gate, a - tr, tr);
      }
    }
  __syncthreads();
  for (int r = w; r < 32; r += 4) {
    float ps = 0.f, pq = 0.f;
#pragma unroll
    for (int t = 0; t < 4; ++t) {
      float v = v_s[r][lane + 64 * t];
      ps += v;
      pq = fmaf(v, v, pq);
    }
    ps = wave_reduce_sum64(ps);
    pq = wave_reduce_sum64(pq);
    if (lane == 0) {
      float mu = ps * (1.f / H);
      mu_s[r] = mu;
      sg_s[r] = rsqrtf(pq * (1.f / H) - mu * mu + LN_EPS);
    }
  }
  __syncthreads();
  {
    const float fgv = fg[tid], fbv = fb[tid];
    for (int r = 0; r < 32; ++r)
      xout_bf[(size_t)(n0 + r) * H + tid] = bf16rne((v_s[r][tid] - mu_s[r]) * sg_s[r] * fgv + fbv);
  }
}

// ---------------- mp layer via MFMA (bf16 in, bf16 residual): x' = LN(x + relu([x,agg]@w+b))
__global__ __launch_bounds__(256) void k_mp_mfma(
    const short* __restrict__ xin_bf, const short* __restrict__ agg_bf,
    const short* __restrict__ wP, const float* __restrict__ bias,
    const float* __restrict__ g, const float* __restrict__ b,
    float* __restrict__ xout_f32, short* __restrict__ xout_bf, int n) {
  __shared__ short As[32][520];
  __shared__ float v_s[32][260];
  __shared__ float mu_s[32], sg_s[32];
  const int tid = threadIdx.x;
  const int lane = tid & 63, w = tid >> 6;
  const int n0 = blockIdx.x * 32;
  for (int q8 = tid; q8 < 32 * 64; q8 += 256) {
    const int idx = q8 << 3;
    const int r = idx >> 9, c = idx & 511;
    const short* src = (c < H) ? &xin_bf[(size_t)(n0 + r) * H + c]
                               : &agg_bf[(size_t)(n0 + r) * H + (c - H)];
    *(int4*)&As[r][c] = *(const int4*)src;
  }
  __syncthreads();
  f32x4 acc[2][4];
#pragma unroll
  for (int rt = 0; rt < 2; ++rt)
#pragma unroll
    for (int ct = 0; ct < 4; ++ct) acc[rt][ct] = (f32x4)0.f;
  const int arow = lane & 15;
  const int koff = (lane >> 4) * 8;
#pragma unroll 4
  for (int ks = 0; ks < 16; ++ks) {
    const int k0 = ks * 32 + koff;
    const bf16x8 a0 = *(const bf16x8*)&As[arow][k0];
    const bf16x8 a1 = *(const bf16x8*)&As[16 + arow][k0];
#pragma unroll
    for (int ct = 0; ct < 4; ++ct) {
      const size_t fo = (((size_t)(w * 4 + ct) * 16 + ks) * 64 + lane) * 8;
      const bf16x8 bw = *(const bf16x8*)&wP[fo];
      acc[0][ct] = __builtin_amdgcn_mfma_f32_16x16x32_bf16(a0, bw, acc[0][ct], 0, 0, 0);
      acc[1][ct] = __builtin_amdgcn_mfma_f32_16x16x32_bf16(a1, bw, acc[1][ct], 0, 0, 0);
    }
  }
#pragma unroll
  for (int rt = 0; rt < 2; ++rt)
#pragma unroll
    for (int ct = 0; ct < 4; ++ct) {
      const int col = w * 64 + ct * 16 + (lane & 15);
      const float bsv = bias[col];
#pragma unroll
      for (int i = 0; i < 4; ++i) {
        const int rl = rt * 16 + (lane >> 4) * 4 + i;
        const float u = fmaxf(acc[rt][ct][i] + bsv, 0.f);
        v_s[rl][col] = bf2f(As[rl][col]) + u;
      }
    }
  __syncthreads();
  for (int r = w; r < 32; r += 4) {
    float ps = 0.f, pq = 0.f;
#pragma unroll
    for (int t = 0; t < 4; ++t) {
      float v = v_s[r][lane + 64 * t];
      ps += v;
      pq = fmaf(v, v, pq);
    }
    ps = wave_reduce_sum64(ps);
    pq = wave_reduce_sum64(pq);
    if (lane == 0) {
      float mu = ps * (1.f / H);
      mu_s[r] = mu;
      sg_s[r] = rsqrtf(pq * (1.f / H) - mu * mu + LN_EPS);
    }
  }
  __syncthreads();
  const float gv = g[tid], bv = b[tid];
  for (int r = 0; r < 32; ++r) {
    const float val = (v_s[r][tid] - mu_s[r]) * sg_s[r] * gv + bv;
    if (xout_f32) xout_f32[(size_t)(n0 + r) * H + tid] = val;
    if (xout_bf) xout_bf[(size_t)(n0 + r) * H + tid] = bf16rne(val);
  }
}

// ---------------- CSR build
__global__ void k_hist(const int* __restrict__ dst, int* __restrict__ hist, int e) {
  int i = blockIdx.x * blockDim.x + threadIdx.x;
  if (i < e) atomicAdd(&hist[dst[i]], 1);
}

__global__ __launch_bounds__(1024) void k_scan(
    const int* __restrict__ hist, int* __restrict__ row_ptr, int* __restrict__ cursor, int n, int e) {
  __shared__ int part[1024];
  const int t = threadIdx.x;
  const int chunk = (n + 1023) / 1024;
  const int lo = t * chunk;
  const int hi = min(lo + chunk, n);
  int s = 0;
  for (int i = lo; i < hi; ++i) s += hist[i];
  part[t] = s;
  __syncthreads();
  for (int d = 1; d < 1024; d <<= 1) {
    int v = (t >= d) ? part[t - d] : 0;
    __syncthreads();
    part[t] += v;
    __syncthreads();
  }
  int run = (t > 0) ? part[t - 1] : 0;
  for (int i = lo; i < hi; ++i) {
    row_ptr[i] = run;
    cursor[i] = run;
    run += hist[i];
  }
  if (t == 1023) row_ptr[n] = e;
}

__global__ void k_fill(const int* __restrict__ adj, int* __restrict__ cursor,
                       int* __restrict__ edge_src, int e) {
  int i = blockIdx.x * blockDim.x + threadIdx.x;
  if (i < e) {
    int s = adj[i], d = adj[e + i];
    int pos = atomicAdd(&cursor[d], 1);
    edge_src[pos] = s;
  }
}

// ---------------- gather (bf16), one wave per dst row, unroll-4 for MLP
__global__ __launch_bounds__(256) void k_gather(
    const short* __restrict__ x, const int* __restrict__ edge_src, const int* __restrict__ row_ptr,
    short* __restrict__ agg, int n) {
  const int wid = threadIdx.x >> 6;
  const int lane = threadIdx.x & 63;
  const int d = blockIdx.x * 4 + wid;
  if (d >= n) return;
  const int beg = row_ptr[d], end = row_ptr[d + 1];
  float4 acc = {0.f, 0.f, 0.f, 0.f};
  int i = beg;
  for (; i + 4 <= end; i += 4) {
    const int s0 = edge_src[i], s1 = edge_src[i + 1], s2 = edge_src[i + 2], s3 = edge_src[i + 3];
    const short4 v0 = *(const short4*)(x + (size_t)s0 * H + lane * 4);
    const short4 v1 = *(const short4*)(x + (size_t)s1 * H + lane * 4);
    const short4 v2 = *(const short4*)(x + (size_t)s2 * H + lane * 4);
    const short4 v3 = *(const short4*)(x + (size_t)s3 * H + lane * 4);
    acc.x += bf2f(v0.x) + bf2f(v1.x) + bf2f(v2.x) + bf2f(v3.x);
    acc.y += bf2f(v0.y) + bf2f(v1.y) + bf2f(v2.y) + bf2f(v3.y);
    acc.z += bf2f(v0.z) + bf2f(v1.z) + bf2f(v2.z) + bf2f(v3.z);
    acc.w += bf2f(v0.w) + bf2f(v1.w) + bf2f(v2.w) + bf2f(v3.w);
  }
  for (; i < end; ++i) {
    const int s = edge_src[i];
    const short4 v = *(const short4*)(x + (size_t)s * H + lane * 4);
    acc.x += bf2f(v.x); acc.y += bf2f(v.y); acc.z += bf2f(v.z); acc.w += bf2f(v.w);
  }
  const float inv = 1.f / fmaxf((float)(end - beg), 1.f);
  short4 o;
  o.x = bf16rne(acc.x * inv); o.y = bf16rne(acc.y * inv);
  o.z = bf16rne(acc.z * inv); o.w = bf16rne(acc.w * inv);
  *(short4*)(agg + (size_t)d * H + lane * 4) = o;
}

extern "C" void kernel_launch(void* const* d_in, const int* in_sizes, int n_in,
                              void* d_out, int out_size, void* d_ws, size_t ws_size,
                              hipStream_t stream) {
  const float* lit = (const float*)d_in[0];
  const float* cf = (const float*)d_in[1];
  const int* mask = (const int*)d_in[2];
  const int* adj = (const int*)d_in[3];
  const float* pe_w1 = (const float*)d_in[4];
  const float* pe_b1 = (const float*)d_in[5];
  const float* pe_w2 = (const float*)d_in[6];
  const float* pe_b2 = (const float*)d_in[7];
  const float* aiw = (const float*)d_in[8];
  const float* aib = (const float*)d_in[9];
  const float* aow = (const float*)d_in[10];
  const float* aob = (const float*)d_in[11];
  const float* attn_ln_g = (const float*)d_in[12];
  const float* attn_ln_b = (const float*)d_in[13];
  const float* gate_w = (const float*)d_in[14];
  const float* gate_b = (const float*)d_in[15];
  const float* trans_w = (const float*)d_in[16];
  const float* trans_b = (const float*)d_in[17];
  const float* fus_ln_g = (const float*)d_in[18];
  const float* fus_ln_b = (const float*)d_in[19];
  const float* mp_w = (const float*)d_in[20];
  const float* mp_b = (const float*)d_in[21];
  const float* mp_ln_g = (const float*)d_in[22];
  const float* mp_ln_b = (const float*)d_in[23];

  const int n = in_sizes[1] / FEAT;   // 20000
  const int e = in_sizes[3] / 2;      // 640000

  float* ws = (float*)d_ws;
  size_t off = 0;
  short* enc_bf16 = (short*)(ws + off); off += (size_t)n * 128;
  short* pm_bf16 = (short*)(ws + off); off += (size_t)n * 512;   // p then m (in-place)
  short* litmean_bf = (short*)(ws + off); off += (size_t)n * 128;
  short* x0_bf = (short*)(ws + off); off += (size_t)n * 128;
  short* x1_bf = (short*)(ws + off); off += (size_t)n * 128;
  short* agg_bf = (short*)(ws + off); off += (size_t)n * 128;
  int* flags = (int*)(ws + off); off += n;
  int* hist = (int*)(ws + off); off += n;
  int* row_ptr = (int*)(ws + off); off += n + 2;
  int* cursor = (int*)(ws + off); off += n;
  int* edge_src = (int*)(ws + off); off += e;
  short* w2P = (short*)(ws + off); off += 256 * 256 / 2;
  short* wqpP = (short*)(ws + off); off += 256 * 1024 / 2;
  short* wbigP = (short*)(ws + off); off += 1024 * 256 / 2;
  short* gwP = (short*)(ws + off); off += 512 * 256 / 2;
  short* twP = (short*)(ws + off); off += 512 * 256 / 2;
  short* mp0P = (short*)(ws + off); off += 512 * 256 / 2;
  short* mp1P = (short*)(ws + off); off += 512 * 256 / 2;
  float* bias_p = ws + off; off += 1024;
  float* bias_out = ws + off; off += 256;

  dim3 blk(256);
  const int histBlocks = (n + 255) / 256;  // 79
  k_prep<<<549 + histBlocks, blk, 0, stream>>>(pe_w2, aiw, aow, aib, aob, gate_w, trans_w, mp_w,
                                               w2P, wqpP, wbigP, gwP, twP, mp0P, mp1P,
                                               bias_p, bias_out, hist, n);

  k_enc_mfma<<<n / 32, blk, 0, stream>>>(cf, pe_w1, pe_b1, w2P, pe_b2, wqpP, bias_p, enc_bf16, pm_bf16, n);
  k_attn<<<n, blk, 0, stream>>>(lit, mask, pm_bf16, pm_bf16, litmean_bf, flags, n);

  // CSR build
  k_hist<<<(e + 255) / 256, blk, 0, stream>>>(adj + e, hist, e);
  k_scan<<<1, 1024, 0, stream>>>(hist, row_ptr, cursor, n, e);
  k_fill<<<(e + 255) / 256, blk, 0, stream>>>(adj, cursor, edge_src, e);

  k_fused<<<n / 32, blk, 0, stream>>>(pm_bf16, wbigP, bias_out, enc_bf16, litmean_bf, flags,
                                      attn_ln_g, attn_ln_b, gwP, twP, gate_b, trans_b,
                                      fus_ln_g, fus_ln_b, x0_bf, n);
  // layer 0
  k_gather<<<(n + 3) / 4, blk, 0, stream>>>(x0_bf, edge_src, row_ptr, agg_bf, n);
  k_mp_mfma<<<n / 32, blk, 0, stream>>>(x0_bf, agg_bf, mp0P, mp_b, mp_ln_g, mp_ln_b,
                                        nullptr, x1_bf, n);
  // layer 1
  k_gather<<<(n + 3) / 4, blk, 0, stream>>>(x1_bf, edge_src, row_ptr, agg_bf, n);
  k_mp_mfma<<<n / 32, blk, 0, stream>>>(x1_bf, agg_bf, mp1P, mp_b + 256, mp_ln_g + 256,
                                        mp_ln_b + 256, (float*)d_out, nullptr, n);
}

// Round 12
// 577.421 us; speedup vs baseline: 1.2553x; 1.0044x over previous
//
#include <hip/hip_runtime.h>
#include <math.h>

#define H 256
#define L 32
#define HEADS 4
#define FEAT 7
#define LN_EPS 1e-5f

typedef __attribute__((ext_vector_type(8))) short bf16x8;
typedef __attribute__((ext_vector_type(4))) float f32x4;
typedef __attribute__((ext_vector_type(4))) float fvec4;  // native vector for nontemporal builtin

__device__ __forceinline__ float wave_reduce_sum64(float v) {
#pragma unroll
  for (int m = 32; m >= 1; m >>= 1) v += __shfl_xor(v, m, 64);
  return v;
}

__device__ __forceinline__ short bf16rne(float f) {
  unsigned u = __float_as_uint(f);
  unsigned r = (u + 0x7FFFu + ((u >> 16) & 1u)) >> 16;
  return (short)r;
}

__device__ __forceinline__ float bf2f(short s) {
  return __uint_as_float(((unsigned)(unsigned short)s) << 16);
}

// ---------------- ONE prep kernel: all weight packing + folded mats + biases + hist zero
// grid: [0,32) w2P | [32,160) wqp | [160,288) wbig | [288,544) 4x pack512 | [544,548) bias_p | 548 bias_out | [549,...) hist=0
__global__ __launch_bounds__(256) void k_prep(
    const float* __restrict__ pe_w2, const float* __restrict__ aiw, const float* __restrict__ aow,
    const float* __restrict__ aib, const float* __restrict__ aob,
    const float* __restrict__ gate_w, const float* __restrict__ trans_w, const float* __restrict__ mp_w,
    short* __restrict__ w2P, short* __restrict__ wqpP, short* __restrict__ wbigP,
    short* __restrict__ gwP, short* __restrict__ twP, short* __restrict__ mp0P, short* __restrict__ mp1P,
    float* __restrict__ bias_p, float* __restrict__ bias_out, int* __restrict__ hist, int n) {
  const int bb = blockIdx.x;
  const int tid = threadIdx.x;
  if (bb < 32) {
    const int t = bb * 256 + tid;
    const int lane = t & 63;
    const int ks = (t >> 6) & 7;
    const int tcol = (t >> 6) >> 3;
    const int j = tcol * 16 + (lane & 15);
    const int k0 = ks * 32 + (lane >> 4) * 8;
    short v[8];
#pragma unroll
    for (int i = 0; i < 8; ++i) v[i] = bf16rne(pe_w2[(size_t)(k0 + i) * 256 + j]);
    *(int4*)&w2P[(size_t)t * 8] = *(int4*)v;
  } else if (bb < 160) {
    // Wqp[k, hc] = 0.125 * sum_d wq[k,h*64+d]*wk[c,h*64+d]  (N=1024, K=256)
    const int t = (bb - 32) * 256 + tid;
    const int lane = t & 63;
    const int ks = (t >> 6) & 7;
    const int tcol = t >> 9;
    const int col = tcol * 16 + (lane & 15);
    const int h = col >> 8, c = col & 255;
    const int k0 = ks * 32 + (lane >> 4) * 8;
    short v[8];
#pragma unroll
    for (int i = 0; i < 8; ++i) {
      const int k = k0 + i;
      float s = 0.f;
      for (int d = 0; d < 64; d += 4) {
        const float4 qa = *(const float4*)&aiw[(size_t)k * 768 + h * 64 + d];
        const float4 ka = *(const float4*)&aiw[(size_t)c * 768 + 256 + h * 64 + d];
        s = fmaf(qa.x, ka.x, fmaf(qa.y, ka.y, fmaf(qa.z, ka.z, fmaf(qa.w, ka.w, s))));
      }
      v[i] = bf16rne(0.125f * s);
    }
    *(int4*)&wqpP[(size_t)t * 8] = *(int4*)v;
  } else if (bb < 288) {
    // Wbig with K-reorder k' = c*4 + h: Wbig[k'][j] = sum_d wv[c,h*64+d]*aow[h*64+d][j]  (N=256, K=1024)
    const int t = (bb - 160) * 256 + tid;
    const int lane = t & 63;
    const int ks = (t >> 6) & 31;
    const int tcol = t >> 11;
    const int j = tcol * 16 + (lane & 15);
    const int k0 = ks * 32 + (lane >> 4) * 8;
    short v[8];
#pragma unroll
    for (int i = 0; i < 8; ++i) {
      const int k = k0 + i;
      const int c = k >> 2, h = k & 3;
      float s = 0.f;
      for (int d = 0; d < 64; ++d)
        s = fmaf(aiw[(size_t)c * 768 + 512 + h * 64 + d], aow[(size_t)(h * 64 + d) * 256 + j], s);
      v[i] = bf16rne(s);
    }
    *(int4*)&wbigP[(size_t)t * 8] = *(int4*)v;
  } else if (bb < 544) {
    const int sub = bb - 288;
    const int mi = sub >> 6;
    const float* W = (mi == 0) ? gate_w : (mi == 1) ? trans_w : (mi == 2) ? mp_w : (mp_w + 512 * 256);
    short* P = (mi == 0) ? gwP : (mi == 1) ? twP : (mi == 2) ? mp0P : mp1P;
    const int t = (sub & 63) * 256 + tid;
    const int lane = t & 63;
    const int ks = (t >> 6) & 15;
    const int tcol = (t >> 6) >> 4;
    const int j = tcol * 16 + (lane & 15);
    const int k0 = ks * 32 + (lane >> 4) * 8;
    short v[8];
#pragma unroll
    for (int i = 0; i < 8; ++i) v[i] = bf16rne(W[(size_t)(k0 + i) * 256 + j]);
    *(int4*)&P[(size_t)t * 8] = *(int4*)v;
  } else if (bb < 548) {
    const int col = (bb - 544) * 256 + tid;  // 1024
    const int h = col >> 8, c = col & 255;
    float s = 0.f;
    for (int d = 0; d < 64; ++d)
      s = fmaf(aib[h * 64 + d], aiw[(size_t)c * 768 + 256 + h * 64 + d], s);
    bias_p[col] = 0.125f * s;
  } else if (bb == 548) {
    const int j = tid;  // 256
    float s = aob[j];
    for (int e2 = 0; e2 < 256; ++e2) s = fmaf(aib[512 + e2], aow[(size_t)e2 * 256 + j], s);
    bias_out[j] = s;
  } else {
    const int i = (bb - 549) * 256 + tid;
    if (i < n) hist[i] = 0;
  }
}

// ---------------- encoder (MFMA): h1 = relu(cf@w1+b1); enc = h1@w2+b2 (bf16); p = enc@Wqp + bias_p
__global__ __launch_bounds__(256) void k_enc_mfma(
    const float* __restrict__ cf, const float* __restrict__ pe_w1, const float* __restrict__ pe_b1,
    const short* __restrict__ w2P, const float* __restrict__ pe_b2,
    const short* __restrict__ wqpP, const float* __restrict__ bias_p,
    short* __restrict__ enc_bf16, short* __restrict__ p_bf16, int n) {
  __shared__ float cfs[32][FEAT];
  __shared__ short h1[32][264];
  __shared__ short encS[32][264];
  const int tid = threadIdx.x;
  const int lane = tid & 63, w = tid >> 6;
  const int n0 = blockIdx.x * 32;
  for (int idx = tid; idx < 32 * FEAT; idx += 256) cfs[idx / FEAT][idx % FEAT] = cf[(size_t)n0 * FEAT + idx];
  __syncthreads();
  {
    const int j = tid;
    float wv[FEAT];
#pragma unroll
    for (int f = 0; f < FEAT; ++f) wv[f] = pe_w1[f * H + j];
    const float b1v = pe_b1[j];
    for (int r = 0; r < 32; ++r) {
      float s = b1v;
#pragma unroll
      for (int f = 0; f < FEAT; ++f) s = fmaf(cfs[r][f], wv[f], s);
      h1[r][j] = bf16rne(fmaxf(s, 0.f));
    }
  }
  __syncthreads();
  const int arow = lane & 15;
  const int koff = (lane >> 4) * 8;
  {
    f32x4 acc[2][4];
#pragma unroll
    for (int rt = 0; rt < 2; ++rt)
#pragma unroll
      for (int ct = 0; ct < 4; ++ct) acc[rt][ct] = (f32x4)0.f;
#pragma unroll
    for (int ks = 0; ks < 8; ++ks) {
      const int k0 = ks * 32 + koff;
      const bf16x8 a0 = *(const bf16x8*)&h1[arow][k0];
      const bf16x8 a1 = *(const bf16x8*)&h1[16 + arow][k0];
#pragma unroll
      for (int ct = 0; ct < 4; ++ct) {
        const size_t fo = (((size_t)(w * 4 + ct) * 8 + ks) * 64 + lane) * 8;
        const bf16x8 b = *(const bf16x8*)&w2P[fo];
        acc[0][ct] = __builtin_amdgcn_mfma_f32_16x16x32_bf16(a0, b, acc[0][ct], 0, 0, 0);
        acc[1][ct] = __builtin_amdgcn_mfma_f32_16x16x32_bf16(a1, b, acc[1][ct], 0, 0, 0);
      }
    }
#pragma unroll
    for (int rt = 0; rt < 2; ++rt)
#pragma unroll
      for (int ct = 0; ct < 4; ++ct) {
        const int col = w * 64 + ct * 16 + (lane & 15);
        const float b2v = pe_b2[col];
#pragma unroll
        for (int i = 0; i < 4; ++i) {
          const int row = rt * 16 + (lane >> 4) * 4 + i;
          const short bv = bf16rne(acc[rt][ct][i] + b2v);
          encS[row][col] = bv;
          enc_bf16[(size_t)(n0 + row) * H + col] = bv;
        }
      }
  }
  __syncthreads();
#pragma unroll
  for (int chunk = 0; chunk < 2; ++chunk) {
    f32x4 acc[2][8];
#pragma unroll
    for (int rt = 0; rt < 2; ++rt)
#pragma unroll
      for (int c8 = 0; c8 < 8; ++c8) acc[rt][c8] = (f32x4)0.f;
#pragma unroll
    for (int ks = 0; ks < 8; ++ks) {
      const int k0 = ks * 32 + koff;
      const bf16x8 a0 = *(const bf16x8*)&encS[arow][k0];
      const bf16x8 a1 = *(const bf16x8*)&encS[16 + arow][k0];
#pragma unroll
      for (int c8 = 0; c8 < 8; ++c8) {
        const int tcol = w * 16 + chunk * 8 + c8;
        const size_t fo = (((size_t)tcol * 8 + ks) * 64 + lane) * 8;
        const bf16x8 b = *(const bf16x8*)&wqpP[fo];
        acc[0][c8] = __builtin_amdgcn_mfma_f32_16x16x32_bf16(a0, b, acc[0][c8], 0, 0, 0);
        acc[1][c8] = __builtin_amdgcn_mfma_f32_16x16x32_bf16(a1, b, acc[1][c8], 0, 0, 0);
      }
    }
#pragma unroll
    for (int rt = 0; rt < 2; ++rt)
#pragma unroll
      for (int c8 = 0; c8 < 8; ++c8) {
        const int col = w * 256 + (chunk * 8 + c8) * 16 + (lane & 15);
        const float bp = bias_p[col];
#pragma unroll
        for (int i = 0; i < 4; ++i) {
          const int row = rt * 16 + (lane >> 4) * 4 + i;
          p_bf16[(size_t)(n0 + row) * 1024 + col] = bf16rne(acc[rt][c8][i] + bp);
        }
      }
  }
}

// ---------------- per-clause attention: nontemporal float4-staged bf16 lit, MFMA scores, coalesced m-store
// m layout: k' = c*4 + h  (matches Wbig packing)
__global__ __launch_bounds__(256) void k_attn(
    const float* __restrict__ lit, const int* __restrict__ mask,
    const short* __restrict__ p_in, short* __restrict__ m_out,
    short* __restrict__ litmean_bf, int* __restrict__ flags, int n) {
  __shared__ short lit_bs[32][264];
  __shared__ float attn_s[32][4];
  __shared__ int validS[32];
  __shared__ int nvalidS;
  const int j = threadIdx.x;
  const int nn = blockIdx.x;
  const fvec4* litrow4 = (const fvec4*)(lit + (size_t)nn * (L * H));
#pragma unroll
  for (int t = 0; t < 8; ++t) {
    const int q = t * 256 + j;
    const int idx = q << 2;
    const int r = idx >> 8, c = idx & 255;
    const fvec4 f = __builtin_nontemporal_load(&litrow4[q]);
    short4 hv;
    hv.x = bf16rne(f.x); hv.y = bf16rne(f.y); hv.z = bf16rne(f.z); hv.w = bf16rne(f.w);
    *(short4*)&lit_bs[r][c] = hv;
  }
  if (j < 32) validS[j] = (mask[(size_t)nn * L + j] != 0) ? 1 : 0;
  __syncthreads();
  if (j == 0) {
    int c = 0;
#pragma unroll
    for (int l = 0; l < 32; ++l) c += validS[l];
    nvalidS = c;
  }
  __syncthreads();
  const int nvalid = nvalidS;
  const bool allm = (nvalid == 0);
  if (j < 64) {
    const int lane = j;
    f32x4 sc0 = (f32x4)0.f, sc1 = (f32x4)0.f;
    const int hh = lane & 3;
    const int krow = (lane >> 4) * 8;
    const short* prow = p_in + (size_t)nn * 1024 + hh * 256;
#pragma unroll
    for (int ks = 0; ks < 8; ++ks) {
      const bf16x8 a = *(const bf16x8*)&prow[ks * 32 + krow];
      const bf16x8 b0 = *(const bf16x8*)&lit_bs[lane & 15][ks * 32 + krow];
      const bf16x8 b1 = *(const bf16x8*)&lit_bs[16 + (lane & 15)][ks * 32 + krow];
      sc0 = __builtin_amdgcn_mfma_f32_16x16x32_bf16(a, b0, sc0, 0, 0, 0);
      sc1 = __builtin_amdgcn_mfma_f32_16x16x32_bf16(a, b1, sc1, 0, 0, 0);
    }
    if (lane < 16) {
      const int l0 = lane, l1 = 16 + lane;
      const bool ok0 = validS[l0] || (allm && l0 == 0);
      const bool ok1 = validS[l1] != 0;
#pragma unroll
      for (int i = 0; i < 4; ++i) {
        float s0 = ok0 ? sc0[i] : -INFINITY;
        float s1 = ok1 ? sc1[i] : -INFINITY;
        float mx = fmaxf(s0, s1);
#pragma unroll
        for (int m = 8; m >= 1; m >>= 1) mx = fmaxf(mx, __shfl_xor(mx, m, 16));
        float e0 = ok0 ? __expf(s0 - mx) : 0.f;
        float e1 = ok1 ? __expf(s1 - mx) : 0.f;
        float sm = e0 + e1;
#pragma unroll
        for (int m = 8; m >= 1; m >>= 1) sm += __shfl_xor(sm, m, 16);
        const float inv = 1.f / sm;
        attn_s[l0][i] = e0 * inv;
        attn_s[l1][i] = e1 * inv;
      }
    }
  }
  __syncthreads();
  {
    const float inv = 1.f / fmaxf((float)nvalid, 1.f);
    float lm = 0.f;
    float mm0 = 0.f, mm1 = 0.f, mm2 = 0.f, mm3 = 0.f;
#pragma unroll
    for (int l = 0; l < 32; ++l) {
      const float lv = bf2f(lit_bs[l][j]);
      if (validS[l]) lm += lv;
      const float4 av = *(const float4*)&attn_s[l][0];
      mm0 = fmaf(av.x, lv, mm0);
      mm1 = fmaf(av.y, lv, mm1);
      mm2 = fmaf(av.z, lv, mm2);
      mm3 = fmaf(av.w, lv, mm3);
    }
    litmean_bf[(size_t)nn * H + j] = bf16rne(lm * inv);
    short4 mv;
    mv.x = bf16rne(mm0); mv.y = bf16rne(mm1); mv.z = bf16rne(mm2); mv.w = bf16rne(mm3);
    *(short4*)&m_out[(size_t)nn * 1024 + j * 4] = mv;  // k' = j*4 + h
  }
  if (j == 0) flags[nn] = allm ? 1 : 0;
}

// ---------------- fused: ctx/out-proj GEMM (K'=1024) + LN1 + gate/trans GEMMs + fusion LN -> x0 bf16
__global__ __launch_bounds__(256) void k_fused(
    const short* __restrict__ m_bf16, const short* __restrict__ wbigP, const float* __restrict__ bias_out,
    const short* __restrict__ enc_bf16, const short* __restrict__ litmean_bf, const int* __restrict__ flags,
    const float* __restrict__ ag, const float* __restrict__ ab,
    const short* __restrict__ gwP, const short* __restrict__ twP,
    const float* __restrict__ gb, const float* __restrict__ tb,
    const float* __restrict__ fg, const float* __restrict__ fb,
    short* __restrict__ xout_bf, int n) {
  __shared__ short As[32][520];
  __shared__ float v_s[32][260];
  __shared__ float mu_s[32], sg_s[32];
  __shared__ int flagS[32];
  const int tid = threadIdx.x;
  const int lane = tid & 63, w = tid >> 6;
  const int n0 = blockIdx.x * 32;
  for (int q8 = tid; q8 < 32 * 32; q8 += 256) {
    const int idx = q8 << 3;
    const int r = idx >> 8, c = idx & 255;
    *(int4*)&As[r][256 + c] = *(const int4*)&enc_bf16[(size_t)(n0 + r) * H + c];
  }
  if (tid < 32) flagS[tid] = flags[n0 + tid];
  const int arow = lane & 15;
  const int koff = (lane >> 4) * 8;
  f32x4 acc[2][4];
#pragma unroll
  for (int rt = 0; rt < 2; ++rt)
#pragma unroll
    for (int ct = 0; ct < 4; ++ct) acc[rt][ct] = (f32x4)0.f;
#pragma unroll 8
  for (int ks = 0; ks < 32; ++ks) {
    const size_t abase = (size_t)(n0 + arow) * 1024 + ks * 32 + koff;
    const bf16x8 a0 = *(const bf16x8*)&m_bf16[abase];
    const bf16x8 a1 = *(const bf16x8*)&m_bf16[abase + 16 * 1024];
#pragma unroll
    for (int ct = 0; ct < 4; ++ct) {
      const size_t fo = (((size_t)(w * 4 + ct) * 32 + ks) * 64 + lane) * 8;
      const bf16x8 bw = *(const bf16x8*)&wbigP[fo];
      acc[0][ct] = __builtin_amdgcn_mfma_f32_16x16x32_bf16(a0, bw, acc[0][ct], 0, 0, 0);
      acc[1][ct] = __builtin_amdgcn_mfma_f32_16x16x32_bf16(a1, bw, acc[1][ct], 0, 0, 0);
    }
  }
  __syncthreads();
#pragma unroll
  for (int rt = 0; rt < 2; ++rt)
#pragma unroll
    for (int ct = 0; ct < 4; ++ct) {
      const int col = w * 64 + ct * 16 + (lane & 15);
      const float bo = bias_out[col];
#pragma unroll
      for (int i = 0; i < 4; ++i) {
        const int row = rt * 16 + (lane >> 4) * 4 + i;
        const float o = flagS[row] ? 0.f : (acc[rt][ct][i] + bo);
        v_s[row][col] = o + bf2f(As[row][256 + col]);
      }
    }
  __syncthreads();
  for (int r = w; r < 32; r += 4) {
    float ps = 0.f, pq = 0.f;
#pragma unroll
    for (int t = 0; t < 4; ++t) {
      float v = v_s[r][lane + 64 * t];
      ps += v;
      pq = fmaf(v, v, pq);
    }
    ps = wave_reduce_sum64(ps);
    pq = wave_reduce_sum64(pq);
    if (lane == 0) {
      float mu = ps * (1.f / H);
      mu_s[r] = mu;
      sg_s[r] = rsqrtf(pq * (1.f / H) - mu * mu + LN_EPS);
    }
  }
  __syncthreads();
  {
    const float agv = ag[tid], abv = ab[tid];
    for (int r = 0; r < 32; ++r) {
      const float val = (v_s[r][tid] - mu_s[r]) * sg_s[r] * agv + abv +
                        bf2f(litmean_bf[(size_t)(n0 + r) * H + tid]);
      As[r][tid] = bf16rne(val);
    }
  }
  __syncthreads();
  f32x4 accg[2][4], acct[2][4];
#pragma unroll
  for (int rt = 0; rt < 2; ++rt)
#pragma unroll
    for (int ct = 0; ct < 4; ++ct) { accg[rt][ct] = (f32x4)0.f; acct[rt][ct] = (f32x4)0.f; }
#pragma unroll 4
  for (int ks = 0; ks < 16; ++ks) {
    const int k0 = ks * 32 + koff;
    const bf16x8 a0 = *(const bf16x8*)&As[arow][k0];
    const bf16x8 a1 = *(const bf16x8*)&As[16 + arow][k0];
#pragma unroll
    for (int ct = 0; ct < 4; ++ct) {
      const size_t fo = (((size_t)(w * 4 + ct) * 16 + ks) * 64 + lane) * 8;
      const bf16x8 bg = *(const bf16x8*)&gwP[fo];
      const bf16x8 bt = *(const bf16x8*)&twP[fo];
      accg[0][ct] = __builtin_amdgcn_mfma_f32_16x16x32_bf16(a0, bg, accg[0][ct], 0, 0, 0);
      accg[1][ct] = __builtin_amdgcn_mfma_f32_16x16x32_bf16(a1, bg, accg[1][ct], 0, 0, 0);
      acct[0][ct] = __builtin_amdgcn_mfma_f32_16x16x32_bf16(a0, bt, acct[0][ct], 0, 0, 0);
      acct[1][ct] = __builtin_amdgcn_mfma_f32_16x16x32_bf16(a1, bt, acct[1][ct], 0, 0, 0);
    }
  }
#pragma unroll
  for (int rt = 0; rt < 2; ++rt)
#pragma unroll
    for (int ct = 0; ct < 4; ++ct) {
      const int col = w * 64 + ct * 16 + (lane & 15);
      const float gbv = gb[col], tbv = tb[col];
#pragma unroll
      for (int i = 0; i < 4; ++i) {
        const int rl = rt * 16 + (lane >> 4) * 4 + i;
        const float gate = 1.f / (1.f + __expf(-(accg[rt][ct][i] + gbv)));
        const float tr = acct[rt][ct][i] + tbv;
        const float a = bf2f(As[rl][col]);
        v_s[rl][col] = fmaf(gate, a - tr, tr);
      }
    }
  __syncthreads();
  for (int r = w; r < 32; r += 4) {
    float ps = 0.f, pq = 0.f;
#pragma unroll
    for (int t = 0; t < 4; ++t) {
      float v = v_s[r][lane + 64 * t];
      ps += v;
      pq = fmaf(v, v, pq);
    }
    ps = wave_reduce_sum64(ps);
    pq = wave_reduce_sum64(pq);
    if (lane == 0) {
      float mu = ps * (1.f / H);
      mu_s[r] = mu;
      sg_s[r] = rsqrtf(pq * (1.f / H) - mu * mu + LN_EPS);
    }
  }
  __syncthreads();
  {
    const float fgv = fg[tid], fbv = fb[tid];
    for (int r = 0; r < 32; ++r)
      xout_bf[(size_t)(n0 + r) * H + tid] = bf16rne((v_s[r][tid] - mu_s[r]) * sg_s[r] * fgv + fbv);
  }
}

// ---------------- mp layer via MFMA, direct-global A operands (no LDS staging):
// x' = LN(x + relu([x,agg]@w+b))
__global__ __launch_bounds__(256) void k_mp_mfma(
    const short* __restrict__ xin_bf, const short* __restrict__ agg_bf,
    const short* __restrict__ wP, const float* __restrict__ bias,
    const float* __restrict__ g, const float* __restrict__ b,
    float* __restrict__ xout_f32, short* __restrict__ xout_bf, int n) {
  __shared__ float v_s[32][260];
  __shared__ float mu_s[32], sg_s[32];
  const int tid = threadIdx.x;
  const int lane = tid & 63, w = tid >> 6;
  const int n0 = blockIdx.x * 32;
  const int arow = lane & 15;
  const int koff = (lane >> 4) * 8;
  f32x4 acc[2][4];
#pragma unroll
  for (int rt = 0; rt < 2; ++rt)
#pragma unroll
    for (int ct = 0; ct < 4; ++ct) acc[rt][ct] = (f32x4)0.f;
  const short* xr0 = xin_bf + (size_t)(n0 + arow) * H;
  const short* xr1 = xin_bf + (size_t)(n0 + 16 + arow) * H;
  const short* gr0 = agg_bf + (size_t)(n0 + arow) * H;
  const short* gr1 = agg_bf + (size_t)(n0 + 16 + arow) * H;
#pragma unroll
  for (int ks = 0; ks < 8; ++ks) {
    const bf16x8 a0 = *(const bf16x8*)&xr0[ks * 32 + koff];
    const bf16x8 a1 = *(const bf16x8*)&xr1[ks * 32 + koff];
#pragma unroll
    for (int ct = 0; ct < 4; ++ct) {
      const size_t fo = (((size_t)(w * 4 + ct) * 16 + ks) * 64 + lane) * 8;
      const bf16x8 bw = *(const bf16x8*)&wP[fo];
      acc[0][ct] = __builtin_amdgcn_mfma_f32_16x16x32_bf16(a0, bw, acc[0][ct], 0, 0, 0);
      acc[1][ct] = __builtin_amdgcn_mfma_f32_16x16x32_bf16(a1, bw, acc[1][ct], 0, 0, 0);
    }
  }
#pragma unroll
  for (int ks = 8; ks < 16; ++ks) {
    const bf16x8 a0 = *(const bf16x8*)&gr0[(ks - 8) * 32 + koff];
    const bf16x8 a1 = *(const bf16x8*)&gr1[(ks - 8) * 32 + koff];
#pragma unroll
    for (int ct = 0; ct < 4; ++ct) {
      const size_t fo = (((size_t)(w * 4 + ct) * 16 + ks) * 64 + lane) * 8;
      const bf16x8 bw = *(const bf16x8*)&wP[fo];
      acc[0][ct] = __builtin_amdgcn_mfma_f32_16x16x32_bf16(a0, bw, acc[0][ct], 0, 0, 0);
      acc[1][ct] = __builtin_amdgcn_mfma_f32_16x16x32_bf16(a1, bw, acc[1][ct], 0, 0, 0);
    }
  }
#pragma unroll
  for (int rt = 0; rt < 2; ++rt)
#pragma unroll
    for (int ct = 0; ct < 4; ++ct) {
      const int col = w * 64 + ct * 16 + (lane & 15);
      const float bsv = bias[col];
#pragma unroll
      for (int i = 0; i < 4; ++i) {
        const int rl = rt * 16 + (lane >> 4) * 4 + i;
        const float u = fmaxf(acc[rt][ct][i] + bsv, 0.f);
        v_s[rl][col] = bf2f(xin_bf[(size_t)(n0 + rl) * H + col]) + u;
      }
    }
  __syncthreads();
  for (int r = w; r < 32; r += 4) {
    float ps = 0.f, pq = 0.f;
#pragma unroll
    for (int t = 0; t < 4; ++t) {
      float v = v_s[r][lane + 64 * t];
      ps += v;
      pq = fmaf(v, v, pq);
    }
    ps = wave_reduce_sum64(ps);
    pq = wave_reduce_sum64(pq);
    if (lane == 0) {
      float mu = ps * (1.f / H);
      mu_s[r] = mu;
      sg_s[r] = rsqrtf(pq * (1.f / H) - mu * mu + LN_EPS);
    }
  }
  __syncthreads();
  const float gv = g[tid], bv = b[tid];
  for (int r = 0; r < 32; ++r) {
    const float val = (v_s[r][tid] - mu_s[r]) * sg_s[r] * gv + bv;
    if (xout_f32) xout_f32[(size_t)(n0 + r) * H + tid] = val;
    if (xout_bf) xout_bf[(size_t)(n0 + r) * H + tid] = bf16rne(val);
  }
}

// ---------------- CSR build
__global__ void k_hist(const int* __restrict__ dst, int* __restrict__ hist, int e) {
  int i = blockIdx.x * blockDim.x + threadIdx.x;
  if (i < e) atomicAdd(&hist[dst[i]], 1);
}

__global__ __launch_bounds__(1024) void k_scan(
    const int* __restrict__ hist, int* __restrict__ row_ptr, int* __restrict__ cursor, int n, int e) {
  __shared__ int part[1024];
  const int t = threadIdx.x;
  const int chunk = (n + 1023) / 1024;
  const int lo = t * chunk;
  const int hi = min(lo + chunk, n);
  int s = 0;
  for (int i = lo; i < hi; ++i) s += hist[i];
  part[t] = s;
  __syncthreads();
  for (int d = 1; d < 1024; d <<= 1) {
    int v = (t >= d) ? part[t - d] : 0;
    __syncthreads();
    part[t] += v;
    __syncthreads();
  }
  int run = (t > 0) ? part[t - 1] : 0;
  for (int i = lo; i < hi; ++i) {
    row_ptr[i] = run;
    cursor[i] = run;
    run += hist[i];
  }
  if (t == 1023) row_ptr[n] = e;
}

__global__ void k_fill(const int* __restrict__ adj, int* __restrict__ cursor,
                       int* __restrict__ edge_src, int e) {
  int i = blockIdx.x * blockDim.x + threadIdx.x;
  if (i < e) {
    int s = adj[i], d = adj[e + i];
    int pos = atomicAdd(&cursor[d], 1);
    edge_src[pos] = s;
  }
}

// ---------------- gather (bf16), one wave per dst row, unroll-8 for MLP
__global__ __launch_bounds__(256) void k_gather(
    const short* __restrict__ x, const int* __restrict__ edge_src, const int* __restrict__ row_ptr,
    short* __restrict__ agg, int n) {
  const int wid = threadIdx.x >> 6;
  const int lane = threadIdx.x & 63;
  const int d = blockIdx.x * 4 + wid;
  if (d >= n) return;
  const int beg = row_ptr[d], end = row_ptr[d + 1];
  float4 acc = {0.f, 0.f, 0.f, 0.f};
  int i = beg;
  for (; i + 8 <= end; i += 8) {
    short4 v[8];
#pragma unroll
    for (int u = 0; u < 8; ++u) {
      const int s = edge_src[i + u];
      v[u] = *(const short4*)(x + (size_t)s * H + lane * 4);
    }
#pragma unroll
    for (int u = 0; u < 8; ++u) {
      acc.x += bf2f(v[u].x);
      acc.y += bf2f(v[u].y);
      acc.z += bf2f(v[u].z);
      acc.w += bf2f(v[u].w);
    }
  }
  for (; i < end; ++i) {
    const int s = edge_src[i];
    const short4 v = *(const short4*)(x + (size_t)s * H + lane * 4);
    acc.x += bf2f(v.x); acc.y += bf2f(v.y); acc.z += bf2f(v.z); acc.w += bf2f(v.w);
  }
  const float inv = 1.f / fmaxf((float)(end - beg), 1.f);
  short4 o;
  o.x = bf16rne(acc.x * inv); o.y = bf16rne(acc.y * inv);
  o.z = bf16rne(acc.z * inv); o.w = bf16rne(acc.w * inv);
  *(short4*)(agg + (size_t)d * H + lane * 4) = o;
}

extern "C" void kernel_launch(void* const* d_in, const int* in_sizes, int n_in,
                              void* d_out, int out_size, void* d_ws, size_t ws_size,
                              hipStream_t stream) {
  const float* lit = (const float*)d_in[0];
  const float* cf = (const float*)d_in[1];
  const int* mask = (const int*)d_in[2];
  const int* adj = (const int*)d_in[3];
  const float* pe_w1 = (const float*)d_in[4];
  const float* pe_b1 = (const float*)d_in[5];
  const float* pe_w2 = (const float*)d_in[6];
  const float* pe_b2 = (const float*)d_in[7];
  const float* aiw = (const float*)d_in[8];
  const float* aib = (const float*)d_in[9];
  const float* aow = (const float*)d_in[10];
  const float* aob = (const float*)d_in[11];
  const float* attn_ln_g = (const float*)d_in[12];
  const float* attn_ln_b = (const float*)d_in[13];
  const float* gate_w = (const float*)d_in[14];
  const float* gate_b = (const float*)d_in[15];
  const float* trans_w = (const float*)d_in[16];
  const float* trans_b = (const float*)d_in[17];
  const float* fus_ln_g = (const float*)d_in[18];
  const float* fus_ln_b = (const float*)d_in[19];
  const float* mp_w = (const float*)d_in[20];
  const float* mp_b = (const float*)d_in[21];
  const float* mp_ln_g = (const float*)d_in[22];
  const float* mp_ln_b = (const float*)d_in[23];

  const int n = in_sizes[1] / FEAT;   // 20000
  const int e = in_sizes[3] / 2;      // 640000

  float* ws = (float*)d_ws;
  size_t off = 0;
  short* enc_bf16 = (short*)(ws + off); off += (size_t)n * 128;
  short* pm_bf16 = (short*)(ws + off); off += (size_t)n * 512;   // p then m (in-place)
  short* litmean_bf = (short*)(ws + off); off += (size_t)n * 128;
  short* x0_bf = (short*)(ws + off); off += (size_t)n * 128;
  short* x1_bf = (short*)(ws + off); off += (size_t)n * 128;
  short* agg_bf = (short*)(ws + off); off += (size_t)n * 128;
  int* flags = (int*)(ws + off); off += n;
  int* hist = (int*)(ws + off); off += n;
  int* row_ptr = (int*)(ws + off); off += n + 2;
  int* cursor = (int*)(ws + off); off += n;
  int* edge_src = (int*)(ws + off); off += e;
  short* w2P = (short*)(ws + off); off += 256 * 256 / 2;
  short* wqpP = (short*)(ws + off); off += 256 * 1024 / 2;
  short* wbigP = (short*)(ws + off); off += 1024 * 256 / 2;
  short* gwP = (short*)(ws + off); off += 512 * 256 / 2;
  short* twP = (short*)(ws + off); off += 512 * 256 / 2;
  short* mp0P = (short*)(ws + off); off += 512 * 256 / 2;
  short* mp1P = (short*)(ws + off); off += 512 * 256 / 2;
  float* bias_p = ws + off; off += 1024;
  float* bias_out = ws + off; off += 256;

  dim3 blk(256);
  const int histBlocks = (n + 255) / 256;  // 79
  k_prep<<<549 + histBlocks, blk, 0, stream>>>(pe_w2, aiw, aow, aib, aob, gate_w, trans_w, mp_w,
                                               w2P, wqpP, wbigP, gwP, twP, mp0P, mp1P,
                                               bias_p, bias_out, hist, n);

  k_enc_mfma<<<n / 32, blk, 0, stream>>>(cf, pe_w1, pe_b1, w2P, pe_b2, wqpP, bias_p, enc_bf16, pm_bf16, n);
  k_attn<<<n, blk, 0, stream>>>(lit, mask, pm_bf16, pm_bf16, litmean_bf, flags, n);

  // CSR build
  k_hist<<<(e + 255) / 256, blk, 0, stream>>>(adj + e, hist, e);
  k_scan<<<1, 1024, 0, stream>>>(hist, row_ptr, cursor, n, e);
  k_fill<<<(e + 255) / 256, blk, 0, stream>>>(adj, cursor, edge_src, e);

  k_fused<<<n / 32, blk, 0, stream>>>(pm_bf16, wbigP, bias_out, enc_bf16, litmean_bf, flags,
                                      attn_ln_g, attn_ln_b, gwP, twP, gate_b, trans_b,
                                      fus_ln_g, fus_ln_b, x0_bf, n);
  // layer 0
  k_gather<<<(n + 3) / 4, blk, 0, stream>>>(x0_bf, edge_src, row_ptr, agg_bf, n);
  k_mp_mfma<<<n / 32, blk, 0, stream>>>(x0_bf, agg_bf, mp0P, mp_b, mp_ln_g, mp_ln_b,
                                        nullptr, x1_bf, n);
  // layer 1
  k_gather<<<(n + 3) / 4, blk, 0, stream>>>(x1_bf, edge_src, row_ptr, agg_bf, n);
  k_mp_mfma<<<n / 32, blk, 0, stream>>>(x1_bf, agg_bf, mp1P, mp_b + 256, mp_ln_g + 256,
                                        mp_ln_b + 256, (float*)d_out, nullptr, n);
}

// Round 13
// 540.065 us; speedup vs baseline: 1.3421x; 1.0692x over previous
//
#include <hip/hip_runtime.h>
#include <math.h>

#define H 256
#define L 32
#define HEADS 4
#define FEAT 7
#define LN_EPS 1e-5f

typedef __attribute__((ext_vector_type(8))) short bf16x8;
typedef __attribute__((ext_vector_type(4))) float f32x4;
typedef __attribute__((ext_vector_type(4))) float fvec4;

__device__ __forceinline__ float wave_reduce_sum64(float v) {
#pragma unroll
  for (int m = 32; m >= 1; m >>= 1) v += __shfl_xor(v, m, 64);
  return v;
}

__device__ __forceinline__ short bf16rne(float f) {
  unsigned u = __float_as_uint(f);
  unsigned r = (u + 0x7FFFu + ((u >> 16) & 1u)) >> 16;
  return (short)r;
}

__device__ __forceinline__ float bf2f(short s) {
  return __uint_as_float(((unsigned)(unsigned short)s) << 16);
}

// ---------------- ONE prep kernel: all weight packing + folded mats + biases + hist zero
__global__ __launch_bounds__(256) void k_prep(
    const float* __restrict__ pe_w2, const float* __restrict__ aiw, const float* __restrict__ aow,
    const float* __restrict__ aib, const float* __restrict__ aob,
    const float* __restrict__ gate_w, const float* __restrict__ trans_w, const float* __restrict__ mp_w,
    short* __restrict__ w2P, short* __restrict__ wqpP, short* __restrict__ wbigP,
    short* __restrict__ gwP, short* __restrict__ twP, short* __restrict__ mp0P, short* __restrict__ mp1P,
    float* __restrict__ bias_p, float* __restrict__ bias_out, int* __restrict__ hist, int n) {
  const int bb = blockIdx.x;
  const int tid = threadIdx.x;
  if (bb < 32) {
    const int t = bb * 256 + tid;
    const int lane = t & 63;
    const int ks = (t >> 6) & 7;
    const int tcol = (t >> 6) >> 3;
    const int j = tcol * 16 + (lane & 15);
    const int k0 = ks * 32 + (lane >> 4) * 8;
    short v[8];
#pragma unroll
    for (int i = 0; i < 8; ++i) v[i] = bf16rne(pe_w2[(size_t)(k0 + i) * 256 + j]);
    *(int4*)&w2P[(size_t)t * 8] = *(int4*)v;
  } else if (bb < 160) {
    const int t = (bb - 32) * 256 + tid;
    const int lane = t & 63;
    const int ks = (t >> 6) & 7;
    const int tcol = t >> 9;
    const int col = tcol * 16 + (lane & 15);
    const int h = col >> 8, c = col & 255;
    const int k0 = ks * 32 + (lane >> 4) * 8;
    short v[8];
#pragma unroll
    for (int i = 0; i < 8; ++i) {
      const int k = k0 + i;
      float s = 0.f;
      for (int d = 0; d < 64; d += 4) {
        const float4 qa = *(const float4*)&aiw[(size_t)k * 768 + h * 64 + d];
        const float4 ka = *(const float4*)&aiw[(size_t)c * 768 + 256 + h * 64 + d];
        s = fmaf(qa.x, ka.x, fmaf(qa.y, ka.y, fmaf(qa.z, ka.z, fmaf(qa.w, ka.w, s))));
      }
      v[i] = bf16rne(0.125f * s);
    }
    *(int4*)&wqpP[(size_t)t * 8] = *(int4*)v;
  } else if (bb < 288) {
    // Wbig with K-reorder k' = c*4 + h
    const int t = (bb - 160) * 256 + tid;
    const int lane = t & 63;
    const int ks = (t >> 6) & 31;
    const int tcol = t >> 11;
    const int j = tcol * 16 + (lane & 15);
    const int k0 = ks * 32 + (lane >> 4) * 8;
    short v[8];
#pragma unroll
    for (int i = 0; i < 8; ++i) {
      const int k = k0 + i;
      const int c = k >> 2, h = k & 3;
      float s = 0.f;
      for (int d = 0; d < 64; ++d)
        s = fmaf(aiw[(size_t)c * 768 + 512 + h * 64 + d], aow[(size_t)(h * 64 + d) * 256 + j], s);
      v[i] = bf16rne(s);
    }
    *(int4*)&wbigP[(size_t)t * 8] = *(int4*)v;
  } else if (bb < 544) {
    const int sub = bb - 288;
    const int mi = sub >> 6;
    const float* W = (mi == 0) ? gate_w : (mi == 1) ? trans_w : (mi == 2) ? mp_w : (mp_w + 512 * 256);
    short* P = (mi == 0) ? gwP : (mi == 1) ? twP : (mi == 2) ? mp0P : mp1P;
    const int t = (sub & 63) * 256 + tid;
    const int lane = t & 63;
    const int ks = (t >> 6) & 15;
    const int tcol = (t >> 6) >> 4;
    const int j = tcol * 16 + (lane & 15);
    const int k0 = ks * 32 + (lane >> 4) * 8;
    short v[8];
#pragma unroll
    for (int i = 0; i < 8; ++i) v[i] = bf16rne(W[(size_t)(k0 + i) * 256 + j]);
    *(int4*)&P[(size_t)t * 8] = *(int4*)v;
  } else if (bb < 548) {
    const int col = (bb - 544) * 256 + tid;
    const int h = col >> 8, c = col & 255;
    float s = 0.f;
    for (int d = 0; d < 64; ++d)
      s = fmaf(aib[h * 64 + d], aiw[(size_t)c * 768 + 256 + h * 64 + d], s);
    bias_p[col] = 0.125f * s;
  } else if (bb == 548) {
    const int j = tid;
    float s = aob[j];
    for (int e2 = 0; e2 < 256; ++e2) s = fmaf(aib[512 + e2], aow[(size_t)e2 * 256 + j], s);
    bias_out[j] = s;
  } else {
    const int i = (bb - 549) * 256 + tid;
    if (i < n) hist[i] = 0;
  }
}

// ---------------- encoder (MFMA) + FUSED hist blocks (blocks >= nEnc do CSR histogram)
__global__ __launch_bounds__(256) void k_enc_mfma(
    const float* __restrict__ cf, const float* __restrict__ pe_w1, const float* __restrict__ pe_b1,
    const short* __restrict__ w2P, const float* __restrict__ pe_b2,
    const short* __restrict__ wqpP, const float* __restrict__ bias_p,
    short* __restrict__ enc_bf16, short* __restrict__ p_bf16, int n,
    const int* __restrict__ adj_dst, int* __restrict__ hist, int e) {
  const int tid = threadIdx.x;
  const int nEnc = n / 32;
  if ((int)blockIdx.x >= nEnc) {
    const int i = ((int)blockIdx.x - nEnc) * 256 + tid;
    if (i < e) atomicAdd(&hist[adj_dst[i]], 1);
    return;
  }
  __shared__ float cfs[32][FEAT];
  __shared__ short h1[32][264];
  __shared__ short encS[32][264];
  const int lane = tid & 63, w = tid >> 6;
  const int n0 = blockIdx.x * 32;
  for (int idx = tid; idx < 32 * FEAT; idx += 256) cfs[idx / FEAT][idx % FEAT] = cf[(size_t)n0 * FEAT + idx];
  __syncthreads();
  {
    const int j = tid;
    float wv[FEAT];
#pragma unroll
    for (int f = 0; f < FEAT; ++f) wv[f] = pe_w1[f * H + j];
    const float b1v = pe_b1[j];
    for (int r = 0; r < 32; ++r) {
      float s = b1v;
#pragma unroll
      for (int f = 0; f < FEAT; ++f) s = fmaf(cfs[r][f], wv[f], s);
      h1[r][j] = bf16rne(fmaxf(s, 0.f));
    }
  }
  __syncthreads();
  const int arow = lane & 15;
  const int koff = (lane >> 4) * 8;
  {
    f32x4 acc[2][4];
#pragma unroll
    for (int rt = 0; rt < 2; ++rt)
#pragma unroll
      for (int ct = 0; ct < 4; ++ct) acc[rt][ct] = (f32x4)0.f;
#pragma unroll
    for (int ks = 0; ks < 8; ++ks) {
      const int k0 = ks * 32 + koff;
      const bf16x8 a0 = *(const bf16x8*)&h1[arow][k0];
      const bf16x8 a1 = *(const bf16x8*)&h1[16 + arow][k0];
#pragma unroll
      for (int ct = 0; ct < 4; ++ct) {
        const size_t fo = (((size_t)(w * 4 + ct) * 8 + ks) * 64 + lane) * 8;
        const bf16x8 b = *(const bf16x8*)&w2P[fo];
        acc[0][ct] = __builtin_amdgcn_mfma_f32_16x16x32_bf16(a0, b, acc[0][ct], 0, 0, 0);
        acc[1][ct] = __builtin_amdgcn_mfma_f32_16x16x32_bf16(a1, b, acc[1][ct], 0, 0, 0);
      }
    }
#pragma unroll
    for (int rt = 0; rt < 2; ++rt)
#pragma unroll
      for (int ct = 0; ct < 4; ++ct) {
        const int col = w * 64 + ct * 16 + (lane & 15);
        const float b2v = pe_b2[col];
#pragma unroll
        for (int i = 0; i < 4; ++i) {
          const int row = rt * 16 + (lane >> 4) * 4 + i;
          const short bv = bf16rne(acc[rt][ct][i] + b2v);
          encS[row][col] = bv;
          enc_bf16[(size_t)(n0 + row) * H + col] = bv;
        }
      }
  }
  __syncthreads();
#pragma unroll
  for (int chunk = 0; chunk < 2; ++chunk) {
    f32x4 acc[2][8];
#pragma unroll
    for (int rt = 0; rt < 2; ++rt)
#pragma unroll
      for (int c8 = 0; c8 < 8; ++c8) acc[rt][c8] = (f32x4)0.f;
#pragma unroll
    for (int ks = 0; ks < 8; ++ks) {
      const int k0 = ks * 32 + koff;
      const bf16x8 a0 = *(const bf16x8*)&encS[arow][k0];
      const bf16x8 a1 = *(const bf16x8*)&encS[16 + arow][k0];
#pragma unroll
      for (int c8 = 0; c8 < 8; ++c8) {
        const int tcol = w * 16 + chunk * 8 + c8;
        const size_t fo = (((size_t)tcol * 8 + ks) * 64 + lane) * 8;
        const bf16x8 b = *(const bf16x8*)&wqpP[fo];
        acc[0][c8] = __builtin_amdgcn_mfma_f32_16x16x32_bf16(a0, b, acc[0][c8], 0, 0, 0);
        acc[1][c8] = __builtin_amdgcn_mfma_f32_16x16x32_bf16(a1, b, acc[1][c8], 0, 0, 0);
      }
    }
#pragma unroll
    for (int rt = 0; rt < 2; ++rt)
#pragma unroll
      for (int c8 = 0; c8 < 8; ++c8) {
        const int col = w * 256 + (chunk * 8 + c8) * 16 + (lane & 15);
        const float bp = bias_p[col];
#pragma unroll
        for (int i = 0; i < 4; ++i) {
          const int row = rt * 16 + (lane >> 4) * 4 + i;
          p_bf16[(size_t)(n0 + row) * 1024 + col] = bf16rne(acc[rt][c8][i] + bp);
        }
      }
  }
}

// ---------------- per-clause attention + FUSED scan block (blockIdx == n does the CSR scan)
__global__ __launch_bounds__(256) void k_attn(
    const float* __restrict__ lit, const int* __restrict__ mask,
    const short* __restrict__ p_in, short* __restrict__ m_out,
    short* __restrict__ litmean_bf, int* __restrict__ flags, int n,
    const int* __restrict__ hist, int* __restrict__ row_ptr, int* __restrict__ cursor, int e) {
  const int j = threadIdx.x;
  const int nn = blockIdx.x;
  if (nn == n) {
    // 256-thread exclusive scan of hist[0..n) -> row_ptr, cursor
    __shared__ int part[256];
    const int chunk = (n + 255) / 256;
    const int lo = j * chunk;
    const int hi = min(lo + chunk, n);
    int s = 0;
    for (int i = lo; i < hi; ++i) s += hist[i];
    part[j] = s;
    __syncthreads();
    for (int d = 1; d < 256; d <<= 1) {
      int v = (j >= d) ? part[j - d] : 0;
      __syncthreads();
      part[j] += v;
      __syncthreads();
    }
    int run = (j > 0) ? part[j - 1] : 0;
    for (int i = lo; i < hi; ++i) {
      row_ptr[i] = run;
      cursor[i] = run;
      run += hist[i];
    }
    if (j == 255) row_ptr[n] = e;
    return;
  }
  __shared__ short lit_bs[32][264];
  __shared__ float attn_s[32][4];
  __shared__ int validS[32];
  __shared__ int nvalidS;
  const fvec4* litrow4 = (const fvec4*)(lit + (size_t)nn * (L * H));
#pragma unroll
  for (int t = 0; t < 8; ++t) {
    const int q = t * 256 + j;
    const int idx = q << 2;
    const int r = idx >> 8, c = idx & 255;
    const fvec4 f = __builtin_nontemporal_load(&litrow4[q]);
    short4 hv;
    hv.x = bf16rne(f.x); hv.y = bf16rne(f.y); hv.z = bf16rne(f.z); hv.w = bf16rne(f.w);
    *(short4*)&lit_bs[r][c] = hv;
  }
  if (j < 32) validS[j] = (mask[(size_t)nn * L + j] != 0) ? 1 : 0;
  __syncthreads();
  if (j == 0) {
    int c = 0;
#pragma unroll
    for (int l = 0; l < 32; ++l) c += validS[l];
    nvalidS = c;
  }
  __syncthreads();
  const int nvalid = nvalidS;
  const bool allm = (nvalid == 0);
  if (j < 64) {
    const int lane = j;
    f32x4 sc0 = (f32x4)0.f, sc1 = (f32x4)0.f;
    const int hh = lane & 3;
    const int krow = (lane >> 4) * 8;
    const short* prow = p_in + (size_t)nn * 1024 + hh * 256;
#pragma unroll
    for (int ks = 0; ks < 8; ++ks) {
      const bf16x8 a = *(const bf16x8*)&prow[ks * 32 + krow];
      const bf16x8 b0 = *(const bf16x8*)&lit_bs[lane & 15][ks * 32 + krow];
      const bf16x8 b1 = *(const bf16x8*)&lit_bs[16 + (lane & 15)][ks * 32 + krow];
      sc0 = __builtin_amdgcn_mfma_f32_16x16x32_bf16(a, b0, sc0, 0, 0, 0);
      sc1 = __builtin_amdgcn_mfma_f32_16x16x32_bf16(a, b1, sc1, 0, 0, 0);
    }
    if (lane < 16) {
      const int l0 = lane, l1 = 16 + lane;
      const bool ok0 = validS[l0] || (allm && l0 == 0);
      const bool ok1 = validS[l1] != 0;
#pragma unroll
      for (int i = 0; i < 4; ++i) {
        float s0 = ok0 ? sc0[i] : -INFINITY;
        float s1 = ok1 ? sc1[i] : -INFINITY;
        float mx = fmaxf(s0, s1);
#pragma unroll
        for (int m = 8; m >= 1; m >>= 1) mx = fmaxf(mx, __shfl_xor(mx, m, 16));
        float e0 = ok0 ? __expf(s0 - mx) : 0.f;
        float e1 = ok1 ? __expf(s1 - mx) : 0.f;
        float sm = e0 + e1;
#pragma unroll
        for (int m = 8; m >= 1; m >>= 1) sm += __shfl_xor(sm, m, 16);
        const float inv = 1.f / sm;
        attn_s[l0][i] = e0 * inv;
        attn_s[l1][i] = e1 * inv;
      }
    }
  }
  __syncthreads();
  {
    const float inv = 1.f / fmaxf((float)nvalid, 1.f);
    float lm = 0.f;
    float mm0 = 0.f, mm1 = 0.f, mm2 = 0.f, mm3 = 0.f;
#pragma unroll
    for (int l = 0; l < 32; ++l) {
      const float lv = bf2f(lit_bs[l][j]);
      if (validS[l]) lm += lv;
      const float4 av = *(const float4*)&attn_s[l][0];
      mm0 = fmaf(av.x, lv, mm0);
      mm1 = fmaf(av.y, lv, mm1);
      mm2 = fmaf(av.z, lv, mm2);
      mm3 = fmaf(av.w, lv, mm3);
    }
    litmean_bf[(size_t)nn * H + j] = bf16rne(lm * inv);
    short4 mv;
    mv.x = bf16rne(mm0); mv.y = bf16rne(mm1); mv.z = bf16rne(mm2); mv.w = bf16rne(mm3);
    *(short4*)&m_out[(size_t)nn * 1024 + j * 4] = mv;  // k' = j*4 + h
  }
  if (j == 0) flags[nn] = allm ? 1 : 0;
}

// ---------------- fused: ctx/out GEMM + LN1 + gate/trans GEMMs + LN2 -> x0 bf16; + FUSED fill blocks
__global__ __launch_bounds__(256) void k_fused(
    const short* __restrict__ m_bf16, const short* __restrict__ wbigP, const float* __restrict__ bias_out,
    const short* __restrict__ enc_bf16, const short* __restrict__ litmean_bf, const int* __restrict__ flags,
    const float* __restrict__ ag, const float* __restrict__ ab,
    const short* __restrict__ gwP, const short* __restrict__ twP,
    const float* __restrict__ gb, const float* __restrict__ tb,
    const float* __restrict__ fg, const float* __restrict__ fb,
    short* __restrict__ xout_bf, int n,
    const int* __restrict__ adj, int* __restrict__ cursor, int* __restrict__ edge_src, int e) {
  const int tid = threadIdx.x;
  const int nFused = n / 32;
  if ((int)blockIdx.x >= nFused) {
    const int i = ((int)blockIdx.x - nFused) * 256 + tid;
    if (i < e) {
      const int s = adj[i], d = adj[e + i];
      const int pos = atomicAdd(&cursor[d], 1);
      edge_src[pos] = s;
    }
    return;
  }
  __shared__ short As[32][520];
  __shared__ float v_s[32][260];
  __shared__ float mu_s[32], sg_s[32];
  __shared__ int flagS[32];
  const int lane = tid & 63, w = tid >> 6;
  const int n0 = blockIdx.x * 32;
  for (int q8 = tid; q8 < 32 * 32; q8 += 256) {
    const int idx = q8 << 3;
    const int r = idx >> 8, c = idx & 255;
    *(int4*)&As[r][256 + c] = *(const int4*)&enc_bf16[(size_t)(n0 + r) * H + c];
  }
  if (tid < 32) flagS[tid] = flags[n0 + tid];
  const int arow = lane & 15;
  const int koff = (lane >> 4) * 8;
  f32x4 acc[2][4];
#pragma unroll
  for (int rt = 0; rt < 2; ++rt)
#pragma unroll
    for (int ct = 0; ct < 4; ++ct) acc[rt][ct] = (f32x4)0.f;
#pragma unroll 8
  for (int ks = 0; ks < 32; ++ks) {
    const size_t abase = (size_t)(n0 + arow) * 1024 + ks * 32 + koff;
    const bf16x8 a0 = *(const bf16x8*)&m_bf16[abase];
    const bf16x8 a1 = *(const bf16x8*)&m_bf16[abase + 16 * 1024];
#pragma unroll
    for (int ct = 0; ct < 4; ++ct) {
      const size_t fo = (((size_t)(w * 4 + ct) * 32 + ks) * 64 + lane) * 8;
      const bf16x8 bw = *(const bf16x8*)&wbigP[fo];
      acc[0][ct] = __builtin_amdgcn_mfma_f32_16x16x32_bf16(a0, bw, acc[0][ct], 0, 0, 0);
      acc[1][ct] = __builtin_amdgcn_mfma_f32_16x16x32_bf16(a1, bw, acc[1][ct], 0, 0, 0);
    }
  }
  __syncthreads();
#pragma unroll
  for (int rt = 0; rt < 2; ++rt)
#pragma unroll
    for (int ct = 0; ct < 4; ++ct) {
      const int col = w * 64 + ct * 16 + (lane & 15);
      const float bo = bias_out[col];
#pragma unroll
      for (int i = 0; i < 4; ++i) {
        const int row = rt * 16 + (lane >> 4) * 4 + i;
        const float o = flagS[row] ? 0.f : (acc[rt][ct][i] + bo);
        v_s[row][col] = o + bf2f(As[row][256 + col]);
      }
    }
  __syncthreads();
  for (int r = w; r < 32; r += 4) {
    float ps = 0.f, pq = 0.f;
#pragma unroll
    for (int t = 0; t < 4; ++t) {
      float v = v_s[r][lane + 64 * t];
      ps += v;
      pq = fmaf(v, v, pq);
    }
    ps = wave_reduce_sum64(ps);
    pq = wave_reduce_sum64(pq);
    if (lane == 0) {
      float mu = ps * (1.f / H);
      mu_s[r] = mu;
      sg_s[r] = rsqrtf(pq * (1.f / H) - mu * mu + LN_EPS);
    }
  }
  __syncthreads();
  {
    const float agv = ag[tid], abv = ab[tid];
    for (int r = 0; r < 32; ++r) {
      const float val = (v_s[r][tid] - mu_s[r]) * sg_s[r] * agv + abv +
                        bf2f(litmean_bf[(size_t)(n0 + r) * H + tid]);
      As[r][tid] = bf16rne(val);
    }
  }
  __syncthreads();
  f32x4 accg[2][4], acct[2][4];
#pragma unroll
  for (int rt = 0; rt < 2; ++rt)
#pragma unroll
    for (int ct = 0; ct < 4; ++ct) { accg[rt][ct] = (f32x4)0.f; acct[rt][ct] = (f32x4)0.f; }
#pragma unroll 4
  for (int ks = 0; ks < 16; ++ks) {
    const int k0 = ks * 32 + koff;
    const bf16x8 a0 = *(const bf16x8*)&As[arow][k0];
    const bf16x8 a1 = *(const bf16x8*)&As[16 + arow][k0];
#pragma unroll
    for (int ct = 0; ct < 4; ++ct) {
      const size_t fo = (((size_t)(w * 4 + ct) * 16 + ks) * 64 + lane) * 8;
      const bf16x8 bg = *(const bf16x8*)&gwP[fo];
      const bf16x8 bt = *(const bf16x8*)&twP[fo];
      accg[0][ct] = __builtin_amdgcn_mfma_f32_16x16x32_bf16(a0, bg, accg[0][ct], 0, 0, 0);
      accg[1][ct] = __builtin_amdgcn_mfma_f32_16x16x32_bf16(a1, bg, accg[1][ct], 0, 0, 0);
      acct[0][ct] = __builtin_amdgcn_mfma_f32_16x16x32_bf16(a0, bt, acct[0][ct], 0, 0, 0);
      acct[1][ct] = __builtin_amdgcn_mfma_f32_16x16x32_bf16(a1, bt, acct[1][ct], 0, 0, 0);
    }
  }
#pragma unroll
  for (int rt = 0; rt < 2; ++rt)
#pragma unroll
    for (int ct = 0; ct < 4; ++ct) {
      const int col = w * 64 + ct * 16 + (lane & 15);
      const float gbv = gb[col], tbv = tb[col];
#pragma unroll
      for (int i = 0; i < 4; ++i) {
        const int rl = rt * 16 + (lane >> 4) * 4 + i;
        const float gate = 1.f / (1.f + __expf(-(accg[rt][ct][i] + gbv)));
        const float tr = acct[rt][ct][i] + tbv;
        const float a = bf2f(As[rl][col]);
        v_s[rl][col] = fmaf(gate, a - tr, tr);
      }
    }
  __syncthreads();
  for (int r = w; r < 32; r += 4) {
    float ps = 0.f, pq = 0.f;
#pragma unroll
    for (int t = 0; t < 4; ++t) {
      float v = v_s[r][lane + 64 * t];
      ps += v;
      pq = fmaf(v, v, pq);
    }
    ps = wave_reduce_sum64(ps);
    pq = wave_reduce_sum64(pq);
    if (lane == 0) {
      float mu = ps * (1.f / H);
      mu_s[r] = mu;
      sg_s[r] = rsqrtf(pq * (1.f / H) - mu * mu + LN_EPS);
    }
  }
  __syncthreads();
  {
    const float fgv = fg[tid], fbv = fb[tid];
    for (int r = 0; r < 32; ++r)
      xout_bf[(size_t)(n0 + r) * H + tid] = bf16rne((v_s[r][tid] - mu_s[r]) * sg_s[r] * fgv + fbv);
  }
}

// ---------------- mp layer via MFMA, direct-global A operands: x' = LN(x + relu([x,agg]@w+b))
__global__ __launch_bounds__(256) void k_mp_mfma(
    const short* __restrict__ xin_bf, const short* __restrict__ agg_bf,
    const short* __restrict__ wP, const float* __restrict__ bias,
    const float* __restrict__ g, const float* __restrict__ b,
    float* __restrict__ xout_f32, short* __restrict__ xout_bf, int n) {
  __shared__ float v_s[32][260];
  __shared__ float mu_s[32], sg_s[32];
  const int tid = threadIdx.x;
  const int lane = tid & 63, w = tid >> 6;
  const int n0 = blockIdx.x * 32;
  const int arow = lane & 15;
  const int koff = (lane >> 4) * 8;
  f32x4 acc[2][4];
#pragma unroll
  for (int rt = 0; rt < 2; ++rt)
#pragma unroll
    for (int ct = 0; ct < 4; ++ct) acc[rt][ct] = (f32x4)0.f;
  const short* xr0 = xin_bf + (size_t)(n0 + arow) * H;
  const short* xr1 = xin_bf + (size_t)(n0 + 16 + arow) * H;
  const short* gr0 = agg_bf + (size_t)(n0 + arow) * H;
  const short* gr1 = agg_bf + (size_t)(n0 + 16 + arow) * H;
#pragma unroll
  for (int ks = 0; ks < 8; ++ks) {
    const bf16x8 a0 = *(const bf16x8*)&xr0[ks * 32 + koff];
    const bf16x8 a1 = *(const bf16x8*)&xr1[ks * 32 + koff];
#pragma unroll
    for (int ct = 0; ct < 4; ++ct) {
      const size_t fo = (((size_t)(w * 4 + ct) * 16 + ks) * 64 + lane) * 8;
      const bf16x8 bw = *(const bf16x8*)&wP[fo];
      acc[0][ct] = __builtin_amdgcn_mfma_f32_16x16x32_bf16(a0, bw, acc[0][ct], 0, 0, 0);
      acc[1][ct] = __builtin_amdgcn_mfma_f32_16x16x32_bf16(a1, bw, acc[1][ct], 0, 0, 0);
    }
  }
#pragma unroll
  for (int ks = 8; ks < 16; ++ks) {
    const bf16x8 a0 = *(const bf16x8*)&gr0[(ks - 8) * 32 + koff];
    const bf16x8 a1 = *(const bf16x8*)&gr1[(ks - 8) * 32 + koff];
#pragma unroll
    for (int ct = 0; ct < 4; ++ct) {
      const size_t fo = (((size_t)(w * 4 + ct) * 16 + ks) * 64 + lane) * 8;
      const bf16x8 bw = *(const bf16x8*)&wP[fo];
      acc[0][ct] = __builtin_amdgcn_mfma_f32_16x16x32_bf16(a0, bw, acc[0][ct], 0, 0, 0);
      acc[1][ct] = __builtin_amdgcn_mfma_f32_16x16x32_bf16(a1, bw, acc[1][ct], 0, 0, 0);
    }
  }
#pragma unroll
  for (int rt = 0; rt < 2; ++rt)
#pragma unroll
    for (int ct = 0; ct < 4; ++ct) {
      const int col = w * 64 + ct * 16 + (lane & 15);
      const float bsv = bias[col];
#pragma unroll
      for (int i = 0; i < 4; ++i) {
        const int rl = rt * 16 + (lane >> 4) * 4 + i;
        const float u = fmaxf(acc[rt][ct][i] + bsv, 0.f);
        v_s[rl][col] = bf2f(xin_bf[(size_t)(n0 + rl) * H + col]) + u;
      }
    }
  __syncthreads();
  for (int r = w; r < 32; r += 4) {
    float ps = 0.f, pq = 0.f;
#pragma unroll
    for (int t = 0; t < 4; ++t) {
      float v = v_s[r][lane + 64 * t];
      ps += v;
      pq = fmaf(v, v, pq);
    }
    ps = wave_reduce_sum64(ps);
    pq = wave_reduce_sum64(pq);
    if (lane == 0) {
      float mu = ps * (1.f / H);
      mu_s[r] = mu;
      sg_s[r] = rsqrtf(pq * (1.f / H) - mu * mu + LN_EPS);
    }
  }
  __syncthreads();
  const float gv = g[tid], bv = b[tid];
  for (int r = 0; r < 32; ++r) {
    const float val = (v_s[r][tid] - mu_s[r]) * sg_s[r] * gv + bv;
    if (xout_f32) xout_f32[(size_t)(n0 + r) * H + tid] = val;
    if (xout_bf) xout_bf[(size_t)(n0 + r) * H + tid] = bf16rne(val);
  }
}

// ---------------- gather (bf16), one wave per dst row, unroll-8
__global__ __launch_bounds__(256) void k_gather(
    const short* __restrict__ x, const int* __restrict__ edge_src, const int* __restrict__ row_ptr,
    short* __restrict__ agg, int n) {
  const int wid = threadIdx.x >> 6;
  const int lane = threadIdx.x & 63;
  const int d = blockIdx.x * 4 + wid;
  if (d >= n) return;
  const int beg = row_ptr[d], end = row_ptr[d + 1];
  float4 acc = {0.f, 0.f, 0.f, 0.f};
  int i = beg;
  for (; i + 8 <= end; i += 8) {
    short4 v[8];
#pragma unroll
    for (int u = 0; u < 8; ++u) {
      const int s = edge_src[i + u];
      v[u] = *(const short4*)(x + (size_t)s * H + lane * 4);
    }
#pragma unroll
    for (int u = 0; u < 8; ++u) {
      acc.x += bf2f(v[u].x);
      acc.y += bf2f(v[u].y);
      acc.z += bf2f(v[u].z);
      acc.w += bf2f(v[u].w);
    }
  }
  for (; i < end; ++i) {
    const int s = edge_src[i];
    const short4 v = *(const short4*)(x + (size_t)s * H + lane * 4);
    acc.x += bf2f(v.x); acc.y += bf2f(v.y); acc.z += bf2f(v.z); acc.w += bf2f(v.w);
  }
  const float inv = 1.f / fmaxf((float)(end - beg), 1.f);
  short4 o;
  o.x = bf16rne(acc.x * inv); o.y = bf16rne(acc.y * inv);
  o.z = bf16rne(acc.z * inv); o.w = bf16rne(acc.w * inv);
  *(short4*)(agg + (size_t)d * H + lane * 4) = o;
}

extern "C" void kernel_launch(void* const* d_in, const int* in_sizes, int n_in,
                              void* d_out, int out_size, void* d_ws, size_t ws_size,
                              hipStream_t stream) {
  const float* lit = (const float*)d_in[0];
  const float* cf = (const float*)d_in[1];
  const int* mask = (const int*)d_in[2];
  const int* adj = (const int*)d_in[3];
  const float* pe_w1 = (const float*)d_in[4];
  const float* pe_b1 = (const float*)d_in[5];
  const float* pe_w2 = (const float*)d_in[6];
  const float* pe_b2 = (const float*)d_in[7];
  const float* aiw = (const float*)d_in[8];
  const float* aib = (const float*)d_in[9];
  const float* aow = (const float*)d_in[10];
  const float* aob = (const float*)d_in[11];
  const float* attn_ln_g = (const float*)d_in[12];
  const float* attn_ln_b = (const float*)d_in[13];
  const float* gate_w = (const float*)d_in[14];
  const float* gate_b = (const float*)d_in[15];
  const float* trans_w = (const float*)d_in[16];
  const float* trans_b = (const float*)d_in[17];
  const float* fus_ln_g = (const float*)d_in[18];
  const float* fus_ln_b = (const float*)d_in[19];
  const float* mp_w = (const float*)d_in[20];
  const float* mp_b = (const float*)d_in[21];
  const float* mp_ln_g = (const float*)d_in[22];
  const float* mp_ln_b = (const float*)d_in[23];

  const int n = in_sizes[1] / FEAT;   // 20000
  const int e = in_sizes[3] / 2;      // 640000

  float* ws = (float*)d_ws;
  size_t off = 0;
  short* enc_bf16 = (short*)(ws + off); off += (size_t)n * 128;
  short* pm_bf16 = (short*)(ws + off); off += (size_t)n * 512;   // p then m (in-place)
  short* litmean_bf = (short*)(ws + off); off += (size_t)n * 128;
  short* x0_bf = (short*)(ws + off); off += (size_t)n * 128;
  short* x1_bf = (short*)(ws + off); off += (size_t)n * 128;
  short* agg_bf = (short*)(ws + off); off += (size_t)n * 128;
  int* flags = (int*)(ws + off); off += n;
  int* hist = (int*)(ws + off); off += n;
  int* row_ptr = (int*)(ws + off); off += n + 2;
  int* cursor = (int*)(ws + off); off += n;
  int* edge_src = (int*)(ws + off); off += e;
  short* w2P = (short*)(ws + off); off += 256 * 256 / 2;
  short* wqpP = (short*)(ws + off); off += 256 * 1024 / 2;
  short* wbigP = (short*)(ws + off); off += 1024 * 256 / 2;
  short* gwP = (short*)(ws + off); off += 512 * 256 / 2;
  short* twP = (short*)(ws + off); off += 512 * 256 / 2;
  short* mp0P = (short*)(ws + off); off += 512 * 256 / 2;
  short* mp1P = (short*)(ws + off); off += 512 * 256 / 2;
  float* bias_p = ws + off; off += 1024;
  float* bias_out = ws + off; off += 256;

  dim3 blk(256);
  const int histBlocks = (n + 255) / 256;   // 79
  const int csrBlocks = (e + 255) / 256;    // 2500
  k_prep<<<549 + histBlocks, blk, 0, stream>>>(pe_w2, aiw, aow, aib, aob, gate_w, trans_w, mp_w,
                                               w2P, wqpP, wbigP, gwP, twP, mp0P, mp1P,
                                               bias_p, bias_out, hist, n);

  // enc + CSR histogram fused
  k_enc_mfma<<<n / 32 + csrBlocks, blk, 0, stream>>>(cf, pe_w1, pe_b1, w2P, pe_b2, wqpP, bias_p,
                                                     enc_bf16, pm_bf16, n, adj + e, hist, e);
  // attn + CSR scan fused (block n)
  k_attn<<<n + 1, blk, 0, stream>>>(lit, mask, pm_bf16, pm_bf16, litmean_bf, flags, n,
                                    hist, row_ptr, cursor, e);
  // fused attention-epilogue GEMMs + CSR fill fused
  k_fused<<<n / 32 + csrBlocks, blk, 0, stream>>>(pm_bf16, wbigP, bias_out, enc_bf16, litmean_bf, flags,
                                                  attn_ln_g, attn_ln_b, gwP, twP, gate_b, trans_b,
                                                  fus_ln_g, fus_ln_b, x0_bf, n,
                                                  adj, cursor, edge_src, e);
  // layer 0
  k_gather<<<(n + 3) / 4, blk, 0, stream>>>(x0_bf, edge_src, row_ptr, agg_bf, n);
  k_mp_mfma<<<n / 32, blk, 0, stream>>>(x0_bf, agg_bf, mp0P, mp_b, mp_ln_g, mp_ln_b,
                                        nullptr, x1_bf, n);
  // layer 1
  k_gather<<<(n + 3) / 4, blk, 0, stream>>>(x1_bf, edge_src, row_ptr, agg_bf, n);
  k_mp_mfma<<<n / 32, blk, 0, stream>>>(x1_bf, agg_bf, mp1P, mp_b + 256, mp_ln_g + 256,
                                        mp_ln_b + 256, (float*)d_out, nullptr, n);
}